// Round 1
// baseline (5348.099 us; speedup 1.0000x reference)
//
#include <hip/hip_runtime.h>
#include <math.h>

// ---------------------------------------------------------------------------
// GraphTransformerLayer: N=50000 nodes, E=640000 edges, D=128, H=8, DH=16
// fp32 throughout (round 1: correctness-first baseline).
//
// ws layout (floats):
//   Q   : [0,        ND)
//   K   : [ND,      2ND)
//   V   : [2ND,     3ND)
//   wV  : [3ND,     4ND)        (memset 0 each call)
//   z   : [4ND, 4ND+8N)         (memset 0)
//   bn  : [4ND+8N, +512)        (memset 0) {bn1_sum,bn1_sq,bn2_sum,bn2_sq}[128]
//   u   : reuses [0, 2ND)  (N x 256, valid after edge stage)
// d_out : t1 -> h1 (in place) -> t2 (in place) -> out (in place)
// ---------------------------------------------------------------------------

// K1: Q/K/V = h @ W^T.  Tile 128 rows x 128 cols, blockIdx.y selects W.
// Thread micro-tile: rows ty+16i, cols tx+16j (i,j<8) -> conflict-free LDS reads.
__global__ __launch_bounds__(256) void k_qkv(
    const float* __restrict__ h,
    const float* __restrict__ WQ, const float* __restrict__ WK, const float* __restrict__ WV,
    float* __restrict__ Qo, float* __restrict__ Ko, float* __restrict__ Vo, int N)
{
    __shared__ float As[128][33];
    __shared__ float Bs[128][33];
    const int tid = threadIdx.x;
    const int ty = tid >> 4, tx = tid & 15;
    const int row0 = blockIdx.x * 128;
    const int w = blockIdx.y;
    const float* __restrict__ W = (w == 0) ? WQ : (w == 1) ? WK : WV;
    float* __restrict__ O = (w == 0) ? Qo : (w == 1) ? Ko : Vo;

    float acc[8][8];
#pragma unroll
    for (int i = 0; i < 8; ++i)
#pragma unroll
        for (int j = 0; j < 8; ++j) acc[i][j] = 0.f;

    for (int kt = 0; kt < 4; ++kt) {
        const int k0 = kt * 32;
#pragma unroll
        for (int t = 0; t < 4; ++t) {
            int idx = tid + t * 256;
            int row = idx >> 3, kq = (idx & 7) * 4;
            int gr = row0 + row;
            float4 av = make_float4(0.f, 0.f, 0.f, 0.f);
            if (gr < N) av = *(const float4*)(h + (size_t)gr * 128 + k0 + kq);
            As[row][kq + 0] = av.x; As[row][kq + 1] = av.y;
            As[row][kq + 2] = av.z; As[row][kq + 3] = av.w;
            float4 bv = *(const float4*)(W + (size_t)row * 128 + k0 + kq);
            Bs[row][kq + 0] = bv.x; Bs[row][kq + 1] = bv.y;
            Bs[row][kq + 2] = bv.z; Bs[row][kq + 3] = bv.w;
        }
        __syncthreads();
#pragma unroll
        for (int kk = 0; kk < 32; ++kk) {
            float a[8], b[8];
#pragma unroll
            for (int i = 0; i < 8; ++i) a[i] = As[ty + 16 * i][kk];
#pragma unroll
            for (int j = 0; j < 8; ++j) b[j] = Bs[tx + 16 * j][kk];
#pragma unroll
            for (int i = 0; i < 8; ++i)
#pragma unroll
                for (int j = 0; j < 8; ++j) acc[i][j] = fmaf(a[i], b[j], acc[i][j]);
        }
        __syncthreads();
    }
#pragma unroll
    for (int i = 0; i < 8; ++i) {
        int gr = row0 + ty + 16 * i;
        if (gr < N) {
#pragma unroll
            for (int j = 0; j < 8; ++j) O[(size_t)gr * 128 + tx + 16 * j] = acc[i][j];
        }
    }
}

// K2: per (edge, head): score = exp(clip(dot(K[s],Q[d])/4, -5, 5));
// atomic scatter wV[d] += V[s]*score, z[d,h] += score.
__global__ __launch_bounds__(256) void k_edge(
    const float* __restrict__ Q, const float* __restrict__ K, const float* __restrict__ V,
    const int* __restrict__ src, const int* __restrict__ dst,
    float* __restrict__ wV, float* __restrict__ z, int E)
{
    int tid = blockIdx.x * 256 + threadIdx.x;
    if (tid >= E * 8) return;
    int e = tid >> 3, hh = tid & 7;
    int s = src[e], d = dst[e];
    const float4* Kp = (const float4*)(K + (size_t)s * 128 + hh * 16);
    const float4* Qp = (const float4*)(Q + (size_t)d * 128 + hh * 16);
    float dv = 0.f;
#pragma unroll
    for (int q = 0; q < 4; ++q) {
        float4 kv = Kp[q], qv = Qp[q];
        dv = fmaf(kv.x, qv.x, dv); dv = fmaf(kv.y, qv.y, dv);
        dv = fmaf(kv.z, qv.z, dv); dv = fmaf(kv.w, qv.w, dv);
    }
    float sc = __expf(fminf(fmaxf(dv * 0.25f, -5.f), 5.f));
    atomicAdd(z + (size_t)d * 8 + hh, sc);
    const float4* Vp = (const float4*)(V + (size_t)s * 128 + hh * 16);
    float* wp = wV + (size_t)d * 128 + hh * 16;
#pragma unroll
    for (int q = 0; q < 4; ++q) {
        float4 vv = Vp[q];
        atomicAdd(wp + q * 4 + 0, vv.x * sc);
        atomicAdd(wp + q * 4 + 1, vv.y * sc);
        atomicAdd(wp + q * 4 + 2, vv.z * sc);
        atomicAdd(wp + q * 4 + 3, vv.w * sc);
    }
}

// K3: t1 = h + (wV/z) @ WO^T + bO; accumulate BN1 column sums/sumsq.
__global__ __launch_bounds__(256) void k_oproj(
    const float* __restrict__ h, const float* __restrict__ wV, const float* __restrict__ z,
    const float* __restrict__ WO, const float* __restrict__ bO,
    float* __restrict__ t1, float* __restrict__ bn, int N)
{
    __shared__ float As[128][33];
    __shared__ float Bs[128][33];
    __shared__ float csum[128], csq[128];
    const int tid = threadIdx.x;
    const int ty = tid >> 4, tx = tid & 15;
    const int row0 = blockIdx.x * 128;
    if (tid < 128) { csum[tid] = 0.f; csq[tid] = 0.f; }

    float acc[8][8];
#pragma unroll
    for (int i = 0; i < 8; ++i)
#pragma unroll
        for (int j = 0; j < 8; ++j) acc[i][j] = 0.f;

    for (int kt = 0; kt < 4; ++kt) {
        const int k0 = kt * 32;
#pragma unroll
        for (int t = 0; t < 4; ++t) {
            int idx = tid + t * 256;
            int row = idx >> 3, kq = (idx & 7) * 4;
            int gr = row0 + row;
            float4 av = make_float4(0.f, 0.f, 0.f, 0.f);
            if (gr < N) {
                av = *(const float4*)(wV + (size_t)gr * 128 + k0 + kq);
                float inv = 1.f / z[(size_t)gr * 8 + ((k0 + kq) >> 4)];
                av.x *= inv; av.y *= inv; av.z *= inv; av.w *= inv;
            }
            As[row][kq + 0] = av.x; As[row][kq + 1] = av.y;
            As[row][kq + 2] = av.z; As[row][kq + 3] = av.w;
            float4 bv = *(const float4*)(WO + (size_t)row * 128 + k0 + kq);
            Bs[row][kq + 0] = bv.x; Bs[row][kq + 1] = bv.y;
            Bs[row][kq + 2] = bv.z; Bs[row][kq + 3] = bv.w;
        }
        __syncthreads();
#pragma unroll
        for (int kk = 0; kk < 32; ++kk) {
            float a[8], b[8];
#pragma unroll
            for (int i = 0; i < 8; ++i) a[i] = As[ty + 16 * i][kk];
#pragma unroll
            for (int j = 0; j < 8; ++j) b[j] = Bs[tx + 16 * j][kk];
#pragma unroll
            for (int i = 0; i < 8; ++i)
#pragma unroll
                for (int j = 0; j < 8; ++j) acc[i][j] = fmaf(a[i], b[j], acc[i][j]);
        }
        __syncthreads();
    }

    float pcs[8], pcq[8];
#pragma unroll
    for (int j = 0; j < 8; ++j) { pcs[j] = 0.f; pcq[j] = 0.f; }
#pragma unroll
    for (int i = 0; i < 8; ++i) {
        int gr = row0 + ty + 16 * i;
        if (gr < N) {
#pragma unroll
            for (int j = 0; j < 8; ++j) {
                int c = tx + 16 * j;
                float v = acc[i][j] + h[(size_t)gr * 128 + c] + bO[c];
                t1[(size_t)gr * 128 + c] = v;
                pcs[j] += v; pcq[j] += v * v;
            }
        }
    }
#pragma unroll
    for (int j = 0; j < 8; ++j) {
        int c = tx + 16 * j;
        atomicAdd(&csum[c], pcs[j]);
        atomicAdd(&csq[c], pcq[j]);
    }
    __syncthreads();
    if (tid < 128) {
        atomicAdd(bn + tid, csum[tid]);
        atomicAdd(bn + 128 + tid, csq[tid]);
    }
}

// K4: h1 = BN1(t1) (written back in place into d_out); u = relu(h1 @ W1^T + b1).
// Tile 64 rows x 256 cols; rows ty+8i (ty<8), cols tx+32j (tx<32).
__global__ __launch_bounds__(256) void k_ffn1(
    float* __restrict__ t1,
    const float* __restrict__ W1, const float* __restrict__ b1,
    const float* __restrict__ g1, const float* __restrict__ bb1,
    const float* __restrict__ bn,
    float* __restrict__ u, int N)
{
    __shared__ float As[64][33];
    __shared__ float Bs[256][33];
    __shared__ float sS[128], sB[128];
    const int tid = threadIdx.x;
    if (tid < 128) {
        float invN = 1.f / (float)N;
        float mu = bn[tid] * invN;
        float var = bn[128 + tid] * invN - mu * mu;
        float scl = g1[tid] * rsqrtf(var + 1e-5f);
        sS[tid] = scl;
        sB[tid] = bb1[tid] - mu * scl;
    }
    __syncthreads();
    const int ty = tid >> 5, tx = tid & 31;
    const int row0 = blockIdx.x * 64;

    float acc[8][8];
#pragma unroll
    for (int i = 0; i < 8; ++i)
#pragma unroll
        for (int j = 0; j < 8; ++j) acc[i][j] = 0.f;

    for (int kt = 0; kt < 4; ++kt) {
        const int k0 = kt * 32;
#pragma unroll
        for (int t = 0; t < 2; ++t) {
            int idx = tid + t * 256;
            int row = idx >> 3, kq = (idx & 7) * 4;
            int gr = row0 + row;
            int c0 = k0 + kq;
            float4 av = make_float4(0.f, 0.f, 0.f, 0.f);
            if (gr < N) {
                av = *(const float4*)(t1 + (size_t)gr * 128 + c0);
                av.x = fmaf(av.x, sS[c0 + 0], sB[c0 + 0]);
                av.y = fmaf(av.y, sS[c0 + 1], sB[c0 + 1]);
                av.z = fmaf(av.z, sS[c0 + 2], sB[c0 + 2]);
                av.w = fmaf(av.w, sS[c0 + 3], sB[c0 + 3]);
                *(float4*)(t1 + (size_t)gr * 128 + c0) = av;   // h1 in place
            }
            As[row][kq + 0] = av.x; As[row][kq + 1] = av.y;
            As[row][kq + 2] = av.z; As[row][kq + 3] = av.w;
        }
#pragma unroll
        for (int t = 0; t < 8; ++t) {
            int idx = tid + t * 256;
            int col = idx >> 3, kq = (idx & 7) * 4;
            float4 bv = *(const float4*)(W1 + (size_t)col * 128 + k0 + kq);
            Bs[col][kq + 0] = bv.x; Bs[col][kq + 1] = bv.y;
            Bs[col][kq + 2] = bv.z; Bs[col][kq + 3] = bv.w;
        }
        __syncthreads();
#pragma unroll
        for (int kk = 0; kk < 32; ++kk) {
            float a[8], b[8];
#pragma unroll
            for (int i = 0; i < 8; ++i) a[i] = As[ty + 8 * i][kk];
#pragma unroll
            for (int j = 0; j < 8; ++j) b[j] = Bs[tx + 32 * j][kk];
#pragma unroll
            for (int i = 0; i < 8; ++i)
#pragma unroll
                for (int j = 0; j < 8; ++j) acc[i][j] = fmaf(a[i], b[j], acc[i][j]);
        }
        __syncthreads();
    }
#pragma unroll
    for (int i = 0; i < 8; ++i) {
        int gr = row0 + ty + 8 * i;
        if (gr < N) {
#pragma unroll
            for (int j = 0; j < 8; ++j) {
                int c = tx + 32 * j;
                u[(size_t)gr * 256 + c] = fmaxf(acc[i][j] + b1[c], 0.f);
            }
        }
    }
}

// K5: t2 = h1 + u @ W2^T + b2 (in place in d_out); accumulate BN2 sums.
__global__ __launch_bounds__(256) void k_ffn2(
    const float* __restrict__ u, float* __restrict__ h1t2,
    const float* __restrict__ W2, const float* __restrict__ b2,
    float* __restrict__ bn, int N)
{
    __shared__ float As[128][33];
    __shared__ float Bs[128][33];
    __shared__ float csum[128], csq[128];
    const int tid = threadIdx.x;
    const int ty = tid >> 4, tx = tid & 15;
    const int row0 = blockIdx.x * 128;
    if (tid < 128) { csum[tid] = 0.f; csq[tid] = 0.f; }

    float acc[8][8];
#pragma unroll
    for (int i = 0; i < 8; ++i)
#pragma unroll
        for (int j = 0; j < 8; ++j) acc[i][j] = 0.f;

    for (int kt = 0; kt < 8; ++kt) {
        const int k0 = kt * 32;
#pragma unroll
        for (int t = 0; t < 4; ++t) {
            int idx = tid + t * 256;
            int row = idx >> 3, kq = (idx & 7) * 4;
            int gr = row0 + row;
            float4 av = make_float4(0.f, 0.f, 0.f, 0.f);
            if (gr < N) av = *(const float4*)(u + (size_t)gr * 256 + k0 + kq);
            As[row][kq + 0] = av.x; As[row][kq + 1] = av.y;
            As[row][kq + 2] = av.z; As[row][kq + 3] = av.w;
            float4 bv = *(const float4*)(W2 + (size_t)row * 256 + k0 + kq);
            Bs[row][kq + 0] = bv.x; Bs[row][kq + 1] = bv.y;
            Bs[row][kq + 2] = bv.z; Bs[row][kq + 3] = bv.w;
        }
        __syncthreads();
#pragma unroll
        for (int kk = 0; kk < 32; ++kk) {
            float a[8], b[8];
#pragma unroll
            for (int i = 0; i < 8; ++i) a[i] = As[ty + 16 * i][kk];
#pragma unroll
            for (int j = 0; j < 8; ++j) b[j] = Bs[tx + 16 * j][kk];
#pragma unroll
            for (int i = 0; i < 8; ++i)
#pragma unroll
                for (int j = 0; j < 8; ++j) acc[i][j] = fmaf(a[i], b[j], acc[i][j]);
        }
        __syncthreads();
    }

    float pcs[8], pcq[8];
#pragma unroll
    for (int j = 0; j < 8; ++j) { pcs[j] = 0.f; pcq[j] = 0.f; }
#pragma unroll
    for (int i = 0; i < 8; ++i) {
        int gr = row0 + ty + 16 * i;
        if (gr < N) {
#pragma unroll
            for (int j = 0; j < 8; ++j) {
                int c = tx + 16 * j;
                float v = acc[i][j] + h1t2[(size_t)gr * 128 + c] + b2[c];
                h1t2[(size_t)gr * 128 + c] = v;   // t2 in place
                pcs[j] += v; pcq[j] += v * v;
            }
        }
    }
#pragma unroll
    for (int j = 0; j < 8; ++j) {
        int c = tx + 16 * j;
        atomicAdd(&csum[c], pcs[j]);
        atomicAdd(&csq[c], pcq[j]);
    }
    __syncthreads();
    if (tid < 128) {
        atomicAdd(bn + 256 + tid, csum[tid]);
        atomicAdd(bn + 384 + tid, csq[tid]);
    }
}

// K6: out = BN2(t2) elementwise, in place in d_out.
__global__ __launch_bounds__(256) void k_bn2(
    float* __restrict__ t2out, const float* __restrict__ bn,
    const float* __restrict__ g2, const float* __restrict__ bb2, int N)
{
    __shared__ float sS[128], sB[128];
    const int tid = threadIdx.x;
    if (tid < 128) {
        float invN = 1.f / (float)N;
        float mu = bn[256 + tid] * invN;
        float var = bn[384 + tid] * invN - mu * mu;
        float scl = g2[tid] * rsqrtf(var + 1e-5f);
        sS[tid] = scl;
        sB[tid] = bb2[tid] - mu * scl;
    }
    __syncthreads();
    size_t idx = (size_t)blockIdx.x * 256 + tid;
    size_t total = (size_t)N * 32;  // N*128/4 float4s
    if (idx < total) {
        int c0 = (int)((idx * 4) & 127);
        float4 v = *(const float4*)(t2out + idx * 4);
        v.x = fmaf(v.x, sS[c0 + 0], sB[c0 + 0]);
        v.y = fmaf(v.y, sS[c0 + 1], sB[c0 + 1]);
        v.z = fmaf(v.z, sS[c0 + 2], sB[c0 + 2]);
        v.w = fmaf(v.w, sS[c0 + 3], sB[c0 + 3]);
        *(float4*)(t2out + idx * 4) = v;
    }
}

extern "C" void kernel_launch(void* const* d_in, const int* in_sizes, int n_in,
                              void* d_out, int out_size, void* d_ws, size_t ws_size,
                              hipStream_t stream)
{
    const float* h   = (const float*)d_in[0];
    const int*   src = (const int*)d_in[1];
    const int*   dst = (const int*)d_in[2];
    const float* WQ  = (const float*)d_in[3];
    const float* WK  = (const float*)d_in[4];
    const float* WV  = (const float*)d_in[5];
    const float* WO  = (const float*)d_in[6];
    const float* bO  = (const float*)d_in[7];
    const float* W1  = (const float*)d_in[8];
    const float* b1  = (const float*)d_in[9];
    const float* W2  = (const float*)d_in[10];
    const float* b2  = (const float*)d_in[11];
    const float* g1  = (const float*)d_in[12];
    const float* bb1 = (const float*)d_in[13];
    const float* g2  = (const float*)d_in[14];
    const float* bb2 = (const float*)d_in[15];
    float* out = (float*)d_out;

    const int N = in_sizes[0] / 128;
    const int E = in_sizes[1];
    const size_t ND = (size_t)N * 128;

    float* ws = (float*)d_ws;
    float* Q  = ws;
    float* K  = ws + ND;
    float* V  = ws + 2 * ND;
    float* wV = ws + 3 * ND;
    float* z  = ws + 4 * ND;
    float* bn = ws + 4 * ND + (size_t)N * 8;
    float* u  = ws;  // reuses Q,K region after the edge stage

    // zero wV, z, bn (contiguous)
    hipMemsetAsync(wV, 0, (ND + (size_t)N * 8 + 512) * sizeof(float), stream);

    dim3 grid_qkv((N + 127) / 128, 3);
    k_qkv<<<grid_qkv, 256, 0, stream>>>(h, WQ, WK, WV, Q, K, V, N);
    k_edge<<<(E * 8 + 255) / 256, 256, 0, stream>>>(Q, K, V, src, dst, wV, z, E);
    k_oproj<<<(N + 127) / 128, 256, 0, stream>>>(h, wV, z, WO, bO, out, bn, N);
    k_ffn1<<<(N + 63) / 64, 256, 0, stream>>>(out, W1, b1, g1, bb1, bn, u, N);
    k_ffn2<<<(N + 127) / 128, 256, 0, stream>>>(u, out, W2, b2, bn, N);
    k_bn2<<<(int)((ND / 4 + 255) / 256), 256, 0, stream>>>(out, bn, g2, bb2, N);
}

// Round 2
// 1092.976 us; speedup vs baseline: 4.8932x; 4.8932x over previous
//
#include <hip/hip_runtime.h>
#include <math.h>

// ---------------------------------------------------------------------------
// GraphTransformerLayer: N=50000 nodes, E=640000 edges, D=128, H=8, DH=16
// Round 2: replace atomic edge-scatter (4.6 ms, 2.6 GB atomic write traffic)
// with device-built CSR + per-node register-accumulated gather attention.
//
// ws layout (4-byte units):
//   Q/attn : [0,       ND)    floats  (Q overwritten in place by attn)
//   K      : [ND,     2ND)    floats
//   V      : [2ND,    3ND)    floats
//   u      : [ND,     3ND)    floats  (N x 256, reuses K/V after attention)
//   cursor : [3ND,        +N)     ints   (memset 0; hist counts -> scatter cursor)
//   bn     : [3ND+N,      +512)   floats (memset 0)
//   rowptr : [3ND+N+512,  +N+1)   ints
//   csr_src: [3ND+2N+513, +E)     ints
// d_out : t1 -> h1 (in place) -> t2 (in place) -> out (in place)
// ---------------------------------------------------------------------------

// K1: Q/K/V = h @ W^T.  Tile 128x128, blockIdx.y selects W.
__global__ __launch_bounds__(256) void k_qkv(
    const float* __restrict__ h,
    const float* __restrict__ WQ, const float* __restrict__ WK, const float* __restrict__ WV,
    float* __restrict__ Qo, float* __restrict__ Ko, float* __restrict__ Vo, int N)
{
    __shared__ float As[128][33];
    __shared__ float Bs[128][33];
    const int tid = threadIdx.x;
    const int ty = tid >> 4, tx = tid & 15;
    const int row0 = blockIdx.x * 128;
    const int w = blockIdx.y;
    const float* __restrict__ W = (w == 0) ? WQ : (w == 1) ? WK : WV;
    float* __restrict__ O = (w == 0) ? Qo : (w == 1) ? Ko : Vo;

    float acc[8][8];
#pragma unroll
    for (int i = 0; i < 8; ++i)
#pragma unroll
        for (int j = 0; j < 8; ++j) acc[i][j] = 0.f;

    for (int kt = 0; kt < 4; ++kt) {
        const int k0 = kt * 32;
#pragma unroll
        for (int t = 0; t < 4; ++t) {
            int idx = tid + t * 256;
            int row = idx >> 3, kq = (idx & 7) * 4;
            int gr = row0 + row;
            float4 av = make_float4(0.f, 0.f, 0.f, 0.f);
            if (gr < N) av = *(const float4*)(h + (size_t)gr * 128 + k0 + kq);
            As[row][kq + 0] = av.x; As[row][kq + 1] = av.y;
            As[row][kq + 2] = av.z; As[row][kq + 3] = av.w;
            float4 bv = *(const float4*)(W + (size_t)row * 128 + k0 + kq);
            Bs[row][kq + 0] = bv.x; Bs[row][kq + 1] = bv.y;
            Bs[row][kq + 2] = bv.z; Bs[row][kq + 3] = bv.w;
        }
        __syncthreads();
#pragma unroll
        for (int kk = 0; kk < 32; ++kk) {
            float a[8], b[8];
#pragma unroll
            for (int i = 0; i < 8; ++i) a[i] = As[ty + 16 * i][kk];
#pragma unroll
            for (int j = 0; j < 8; ++j) b[j] = Bs[tx + 16 * j][kk];
#pragma unroll
            for (int i = 0; i < 8; ++i)
#pragma unroll
                for (int j = 0; j < 8; ++j) acc[i][j] = fmaf(a[i], b[j], acc[i][j]);
        }
        __syncthreads();
    }
#pragma unroll
    for (int i = 0; i < 8; ++i) {
        int gr = row0 + ty + 16 * i;
        if (gr < N) {
#pragma unroll
            for (int j = 0; j < 8; ++j) O[(size_t)gr * 128 + tx + 16 * j] = acc[i][j];
        }
    }
}

// CSR build, step 1: histogram of dst into cursor (pre-zeroed).
__global__ __launch_bounds__(256) void k_hist(
    const int* __restrict__ dst, int* __restrict__ cursor, int E)
{
    int e = blockIdx.x * 256 + threadIdx.x;
    if (e < E) atomicAdd(&cursor[dst[e]], 1);
}

// CSR build, step 2: single-block exclusive scan. cnt aliases cursor (read
// count before overwriting with the running prefix).
__global__ __launch_bounds__(1024) void k_scan(
    const int* cnt, int* rowptr, int* cursor, int N)
{
    __shared__ int part[1024];
    const int t = threadIdx.x;
    const int chunk = (N + 1023) >> 10;
    const int b0 = t * chunk;
    int lsum = 0;
    for (int i = 0; i < chunk; ++i) {
        int idx = b0 + i;
        if (idx < N) lsum += cnt[idx];
    }
    part[t] = lsum;
    __syncthreads();
    for (int off = 1; off < 1024; off <<= 1) {
        int v = (t >= off) ? part[t - off] : 0;
        __syncthreads();
        part[t] += v;
        __syncthreads();
    }
    int run = (t == 0) ? 0 : part[t - 1];
    for (int i = 0; i < chunk; ++i) {
        int idx = b0 + i;
        if (idx < N) {
            int cv = cnt[idx];          // read BEFORE cursor overwrite (alias)
            rowptr[idx] = run;
            cursor[idx] = run;
            run += cv;
        }
    }
    if (t == 1023) rowptr[N] = part[1023];
}

// CSR build, step 3: scatter src ids into per-dst segments.
__global__ __launch_bounds__(256) void k_scatter(
    const int* __restrict__ src, const int* __restrict__ dst,
    int* __restrict__ cursor, int* __restrict__ csr_src, int E)
{
    int e = blockIdx.x * 256 + threadIdx.x;
    if (e < E) {
        int pos = atomicAdd(&cursor[dst[e]], 1);
        csr_src[pos] = src[e];
    }
}

// K2: gather attention. 128 threads per node (2 nodes / 256-block).
// Lane c owns channel c; per-head (16-ch) dot via shfl_xor; z stays in a
// register per lane (identical within each 16-lane head group), so the
// normalization is a per-lane divide. attn overwrites Q in place.
__global__ __launch_bounds__(256) void k_attn(
    float* __restrict__ QA, const float* __restrict__ K, const float* __restrict__ V,
    const int* __restrict__ rowptr, const int* __restrict__ csr_src, int N)
{
    const int node = blockIdx.x * 2 + (threadIdx.x >> 7);
    const int c = threadIdx.x & 127;
    if (node >= N) return;
    const int beg = rowptr[node], end = rowptr[node + 1];
    const float q = QA[(size_t)node * 128 + c];
    float acc = 0.f, zacc = 0.f;
    for (int i = beg; i < end; ++i) {
        int s = csr_src[i];
        float k = K[(size_t)s * 128 + c];
        float p = q * k;
        p += __shfl_xor(p, 8, 16);
        p += __shfl_xor(p, 4, 16);
        p += __shfl_xor(p, 2, 16);
        p += __shfl_xor(p, 1, 16);
        float sc = __expf(fminf(fmaxf(p * 0.25f, -5.f), 5.f));
        float v = V[(size_t)s * 128 + c];
        acc = fmaf(v, sc, acc);
        zacc += sc;
    }
    QA[(size_t)node * 128 + c] = acc / zacc;
}

// K3: t1 = h + attn @ WO^T + bO; accumulate BN1 column sums/sumsq.
__global__ __launch_bounds__(256) void k_oproj(
    const float* __restrict__ h, const float* __restrict__ attn,
    const float* __restrict__ WO, const float* __restrict__ bO,
    float* __restrict__ t1, float* __restrict__ bn, int N)
{
    __shared__ float As[128][33];
    __shared__ float Bs[128][33];
    __shared__ float csum[128], csq[128];
    const int tid = threadIdx.x;
    const int ty = tid >> 4, tx = tid & 15;
    const int row0 = blockIdx.x * 128;
    if (tid < 128) { csum[tid] = 0.f; csq[tid] = 0.f; }

    float acc[8][8];
#pragma unroll
    for (int i = 0; i < 8; ++i)
#pragma unroll
        for (int j = 0; j < 8; ++j) acc[i][j] = 0.f;

    for (int kt = 0; kt < 4; ++kt) {
        const int k0 = kt * 32;
#pragma unroll
        for (int t = 0; t < 4; ++t) {
            int idx = tid + t * 256;
            int row = idx >> 3, kq = (idx & 7) * 4;
            int gr = row0 + row;
            float4 av = make_float4(0.f, 0.f, 0.f, 0.f);
            if (gr < N) av = *(const float4*)(attn + (size_t)gr * 128 + k0 + kq);
            As[row][kq + 0] = av.x; As[row][kq + 1] = av.y;
            As[row][kq + 2] = av.z; As[row][kq + 3] = av.w;
            float4 bv = *(const float4*)(WO + (size_t)row * 128 + k0 + kq);
            Bs[row][kq + 0] = bv.x; Bs[row][kq + 1] = bv.y;
            Bs[row][kq + 2] = bv.z; Bs[row][kq + 3] = bv.w;
        }
        __syncthreads();
#pragma unroll
        for (int kk = 0; kk < 32; ++kk) {
            float a[8], b[8];
#pragma unroll
            for (int i = 0; i < 8; ++i) a[i] = As[ty + 16 * i][kk];
#pragma unroll
            for (int j = 0; j < 8; ++j) b[j] = Bs[tx + 16 * j][kk];
#pragma unroll
            for (int i = 0; i < 8; ++i)
#pragma unroll
                for (int j = 0; j < 8; ++j) acc[i][j] = fmaf(a[i], b[j], acc[i][j]);
        }
        __syncthreads();
    }

    float pcs[8], pcq[8];
#pragma unroll
    for (int j = 0; j < 8; ++j) { pcs[j] = 0.f; pcq[j] = 0.f; }
#pragma unroll
    for (int i = 0; i < 8; ++i) {
        int gr = row0 + ty + 16 * i;
        if (gr < N) {
#pragma unroll
            for (int j = 0; j < 8; ++j) {
                int c = tx + 16 * j;
                float v = acc[i][j] + h[(size_t)gr * 128 + c] + bO[c];
                t1[(size_t)gr * 128 + c] = v;
                pcs[j] += v; pcq[j] += v * v;
            }
        }
    }
#pragma unroll
    for (int j = 0; j < 8; ++j) {
        int c = tx + 16 * j;
        atomicAdd(&csum[c], pcs[j]);
        atomicAdd(&csq[c], pcq[j]);
    }
    __syncthreads();
    if (tid < 128) {
        atomicAdd(bn + tid, csum[tid]);
        atomicAdd(bn + 128 + tid, csq[tid]);
    }
}

// K4: h1 = BN1(t1) in place; u = relu(h1 @ W1^T + b1). 64x256 tile.
__global__ __launch_bounds__(256) void k_ffn1(
    float* __restrict__ t1,
    const float* __restrict__ W1, const float* __restrict__ b1,
    const float* __restrict__ g1, const float* __restrict__ bb1,
    const float* __restrict__ bn,
    float* __restrict__ u, int N)
{
    __shared__ float As[64][33];
    __shared__ float Bs[256][33];
    __shared__ float sS[128], sB[128];
    const int tid = threadIdx.x;
    if (tid < 128) {
        float invN = 1.f / (float)N;
        float mu = bn[tid] * invN;
        float var = bn[128 + tid] * invN - mu * mu;
        float scl = g1[tid] * rsqrtf(var + 1e-5f);
        sS[tid] = scl;
        sB[tid] = bb1[tid] - mu * scl;
    }
    __syncthreads();
    const int ty = tid >> 5, tx = tid & 31;
    const int row0 = blockIdx.x * 64;

    float acc[8][8];
#pragma unroll
    for (int i = 0; i < 8; ++i)
#pragma unroll
        for (int j = 0; j < 8; ++j) acc[i][j] = 0.f;

    for (int kt = 0; kt < 4; ++kt) {
        const int k0 = kt * 32;
#pragma unroll
        for (int t = 0; t < 2; ++t) {
            int idx = tid + t * 256;
            int row = idx >> 3, kq = (idx & 7) * 4;
            int gr = row0 + row;
            int c0 = k0 + kq;
            float4 av = make_float4(0.f, 0.f, 0.f, 0.f);
            if (gr < N) {
                av = *(const float4*)(t1 + (size_t)gr * 128 + c0);
                av.x = fmaf(av.x, sS[c0 + 0], sB[c0 + 0]);
                av.y = fmaf(av.y, sS[c0 + 1], sB[c0 + 1]);
                av.z = fmaf(av.z, sS[c0 + 2], sB[c0 + 2]);
                av.w = fmaf(av.w, sS[c0 + 3], sB[c0 + 3]);
                *(float4*)(t1 + (size_t)gr * 128 + c0) = av;   // h1 in place
            }
            As[row][kq + 0] = av.x; As[row][kq + 1] = av.y;
            As[row][kq + 2] = av.z; As[row][kq + 3] = av.w;
        }
#pragma unroll
        for (int t = 0; t < 8; ++t) {
            int idx = tid + t * 256;
            int col = idx >> 3, kq = (idx & 7) * 4;
            float4 bv = *(const float4*)(W1 + (size_t)col * 128 + k0 + kq);
            Bs[col][kq + 0] = bv.x; Bs[col][kq + 1] = bv.y;
            Bs[col][kq + 2] = bv.z; Bs[col][kq + 3] = bv.w;
        }
        __syncthreads();
#pragma unroll
        for (int kk = 0; kk < 32; ++kk) {
            float a[8], b[8];
#pragma unroll
            for (int i = 0; i < 8; ++i) a[i] = As[ty + 8 * i][kk];
#pragma unroll
            for (int j = 0; j < 8; ++j) b[j] = Bs[tx + 32 * j][kk];
#pragma unroll
            for (int i = 0; i < 8; ++i)
#pragma unroll
                for (int j = 0; j < 8; ++j) acc[i][j] = fmaf(a[i], b[j], acc[i][j]);
        }
        __syncthreads();
    }
#pragma unroll
    for (int i = 0; i < 8; ++i) {
        int gr = row0 + ty + 8 * i;
        if (gr < N) {
#pragma unroll
            for (int j = 0; j < 8; ++j) {
                int c = tx + 32 * j;
                u[(size_t)gr * 256 + c] = fmaxf(acc[i][j] + b1[c], 0.f);
            }
        }
    }
}

// K5: t2 = h1 + u @ W2^T + b2 in place; accumulate BN2 sums.
__global__ __launch_bounds__(256) void k_ffn2(
    const float* __restrict__ u, float* __restrict__ h1t2,
    const float* __restrict__ W2, const float* __restrict__ b2,
    float* __restrict__ bn, int N)
{
    __shared__ float As[128][33];
    __shared__ float Bs[128][33];
    __shared__ float csum[128], csq[128];
    const int tid = threadIdx.x;
    const int ty = tid >> 4, tx = tid & 15;
    const int row0 = blockIdx.x * 128;
    if (tid < 128) { csum[tid] = 0.f; csq[tid] = 0.f; }

    float acc[8][8];
#pragma unroll
    for (int i = 0; i < 8; ++i)
#pragma unroll
        for (int j = 0; j < 8; ++j) acc[i][j] = 0.f;

    for (int kt = 0; kt < 8; ++kt) {
        const int k0 = kt * 32;
#pragma unroll
        for (int t = 0; t < 4; ++t) {
            int idx = tid + t * 256;
            int row = idx >> 3, kq = (idx & 7) * 4;
            int gr = row0 + row;
            float4 av = make_float4(0.f, 0.f, 0.f, 0.f);
            if (gr < N) av = *(const float4*)(u + (size_t)gr * 256 + k0 + kq);
            As[row][kq + 0] = av.x; As[row][kq + 1] = av.y;
            As[row][kq + 2] = av.z; As[row][kq + 3] = av.w;
            float4 bv = *(const float4*)(W2 + (size_t)row * 256 + k0 + kq);
            Bs[row][kq + 0] = bv.x; Bs[row][kq + 1] = bv.y;
            Bs[row][kq + 2] = bv.z; Bs[row][kq + 3] = bv.w;
        }
        __syncthreads();
#pragma unroll
        for (int kk = 0; kk < 32; ++kk) {
            float a[8], b[8];
#pragma unroll
            for (int i = 0; i < 8; ++i) a[i] = As[ty + 16 * i][kk];
#pragma unroll
            for (int j = 0; j < 8; ++j) b[j] = Bs[tx + 16 * j][kk];
#pragma unroll
            for (int i = 0; i < 8; ++i)
#pragma unroll
                for (int j = 0; j < 8; ++j) acc[i][j] = fmaf(a[i], b[j], acc[i][j]);
        }
        __syncthreads();
    }

    float pcs[8], pcq[8];
#pragma unroll
    for (int j = 0; j < 8; ++j) { pcs[j] = 0.f; pcq[j] = 0.f; }
#pragma unroll
    for (int i = 0; i < 8; ++i) {
        int gr = row0 + ty + 16 * i;
        if (gr < N) {
#pragma unroll
            for (int j = 0; j < 8; ++j) {
                int c = tx + 16 * j;
                float v = acc[i][j] + h1t2[(size_t)gr * 128 + c] + b2[c];
                h1t2[(size_t)gr * 128 + c] = v;   // t2 in place
                pcs[j] += v; pcq[j] += v * v;
            }
        }
    }
#pragma unroll
    for (int j = 0; j < 8; ++j) {
        int c = tx + 16 * j;
        atomicAdd(&csum[c], pcs[j]);
        atomicAdd(&csq[c], pcq[j]);
    }
    __syncthreads();
    if (tid < 128) {
        atomicAdd(bn + 256 + tid, csum[tid]);
        atomicAdd(bn + 384 + tid, csq[tid]);
    }
}

// K6: out = BN2(t2) elementwise, in place.
__global__ __launch_bounds__(256) void k_bn2(
    float* __restrict__ t2out, const float* __restrict__ bn,
    const float* __restrict__ g2, const float* __restrict__ bb2, int N)
{
    __shared__ float sS[128], sB[128];
    const int tid = threadIdx.x;
    if (tid < 128) {
        float invN = 1.f / (float)N;
        float mu = bn[256 + tid] * invN;
        float var = bn[384 + tid] * invN - mu * mu;
        float scl = g2[tid] * rsqrtf(var + 1e-5f);
        sS[tid] = scl;
        sB[tid] = bb2[tid] - mu * scl;
    }
    __syncthreads();
    size_t idx = (size_t)blockIdx.x * 256 + tid;
    size_t total = (size_t)N * 32;
    if (idx < total) {
        int c0 = (int)((idx * 4) & 127);
        float4 v = *(const float4*)(t2out + idx * 4);
        v.x = fmaf(v.x, sS[c0 + 0], sB[c0 + 0]);
        v.y = fmaf(v.y, sS[c0 + 1], sB[c0 + 1]);
        v.z = fmaf(v.z, sS[c0 + 2], sB[c0 + 2]);
        v.w = fmaf(v.w, sS[c0 + 3], sB[c0 + 3]);
        *(float4*)(t2out + idx * 4) = v;
    }
}

extern "C" void kernel_launch(void* const* d_in, const int* in_sizes, int n_in,
                              void* d_out, int out_size, void* d_ws, size_t ws_size,
                              hipStream_t stream)
{
    const float* h   = (const float*)d_in[0];
    const int*   src = (const int*)d_in[1];
    const int*   dst = (const int*)d_in[2];
    const float* WQ  = (const float*)d_in[3];
    const float* WK  = (const float*)d_in[4];
    const float* WV  = (const float*)d_in[5];
    const float* WO  = (const float*)d_in[6];
    const float* bO  = (const float*)d_in[7];
    const float* W1  = (const float*)d_in[8];
    const float* b1  = (const float*)d_in[9];
    const float* W2  = (const float*)d_in[10];
    const float* b2  = (const float*)d_in[11];
    const float* g1  = (const float*)d_in[12];
    const float* bb1 = (const float*)d_in[13];
    const float* g2  = (const float*)d_in[14];
    const float* bb2 = (const float*)d_in[15];
    float* out = (float*)d_out;

    const int N = in_sizes[0] / 128;
    const int E = in_sizes[1];
    const size_t ND = (size_t)N * 128;

    float* ws = (float*)d_ws;
    float* Q  = ws;              // becomes attn in place
    float* K  = ws + ND;
    float* V  = ws + 2 * ND;
    float* u  = ws + ND;         // reuses K,V region after attention
    int*   cursor  = (int*)(ws + 3 * ND);
    float* bn      = ws + 3 * ND + N;                  // 512 floats
    int*   rowptr  = (int*)(ws + 3 * ND + N + 512);    // N+1 ints
    int*   csr_src = (int*)(ws + 3 * ND + N + 512 + (N + 1));

    // zero cursor + bn (contiguous)
    hipMemsetAsync(cursor, 0, ((size_t)N + 512) * sizeof(int), stream);

    dim3 grid_qkv((N + 127) / 128, 3);
    k_qkv<<<grid_qkv, 256, 0, stream>>>(h, WQ, WK, WV, Q, K, V, N);
    k_hist<<<(E + 255) / 256, 256, 0, stream>>>(dst, cursor, E);
    k_scan<<<1, 1024, 0, stream>>>(cursor, rowptr, cursor, N);
    k_scatter<<<(E + 255) / 256, 256, 0, stream>>>(src, dst, cursor, csr_src, E);
    k_attn<<<(N + 1) / 2, 256, 0, stream>>>(Q, K, V, rowptr, csr_src, N);
    k_oproj<<<(N + 127) / 128, 256, 0, stream>>>(h, Q, WO, bO, out, bn, N);
    k_ffn1<<<(N + 63) / 64, 256, 0, stream>>>(out, W1, b1, g1, bb1, bn, u, N);
    k_ffn2<<<(N + 127) / 128, 256, 0, stream>>>(u, out, W2, b2, bn, N);
    k_bn2<<<(int)((ND / 4 + 255) / 256), 256, 0, stream>>>(out, bn, g2, bb2, N);
}

// Round 3
// 487.204 us; speedup vs baseline: 10.9771x; 2.2434x over previous
//
#include <hip/hip_runtime.h>
#include <math.h>

// ---------------------------------------------------------------------------
// GraphTransformerLayer N=50000, E=640000, D=128, H=8, DH=16  (gfx950)
// Round 3: bf16 MFMA (16x16x32) for all GEMMs, fragment-ordered global
// layouts (no LDS staging needed, K=128 fits), bf16 gather attention,
// BN1 folded into W1/bias.
//
// Fragment order for an MxK slab (M=128, K=KB*32):
//   elem index = ((kb*8 + mtile)*64 + lane)*8 + j
//   row = mtile*16 + (lane&15),  col = kb*32 + (lane>>4)*8 + j
// MFMA 16x16x32 bf16: A[m=lane&15][k=(lane>>4)*8+j], B likewise (B = W rows,
// W stored [out][in] row-major = [N][K]).  C/D: col=lane&15, row=(lane>>4)*4+reg.
// ---------------------------------------------------------------------------

#define ND128 16384
typedef __attribute__((ext_vector_type(8))) short bf8;
typedef __attribute__((ext_vector_type(4))) float f4;

__device__ __forceinline__ unsigned short f2bf(float f) {
    unsigned x = __float_as_uint(f);
    unsigned r = (x + 0x7fffu + ((x >> 16) & 1u)) >> 16;
    return (unsigned short)r;
}
__device__ __forceinline__ float bf2f(unsigned short u) {
    return __uint_as_float(((unsigned)u) << 16);
}

// --- cast h (fp32 row-major) -> hb (bf16 fragment order, zero-padded rows) --
__global__ __launch_bounds__(256) void k_cast_h(
    const float* __restrict__ h, short* __restrict__ hb, int N)
{
    const int slab = blockIdx.x;
    const int tid = threadIdx.x;
#pragma unroll
    for (int it = 0; it < 8; ++it) {
        int cid = it * 256 + tid;              // 0..2047
        int lane = cid & 63;
        int m = (cid >> 6) & 7;
        int kb = cid >> 9;
        int row = slab * 128 + m * 16 + (lane & 15);
        int col = kb * 32 + (lane >> 4) * 8;
        short o8[8];
        if (row < N) {
            const float* p = h + (size_t)row * 128 + col;
            float4 f0 = *(const float4*)p;
            float4 f1 = *(const float4*)(p + 4);
            o8[0] = (short)f2bf(f0.x); o8[1] = (short)f2bf(f0.y);
            o8[2] = (short)f2bf(f0.z); o8[3] = (short)f2bf(f0.w);
            o8[4] = (short)f2bf(f1.x); o8[5] = (short)f2bf(f1.y);
            o8[6] = (short)f2bf(f1.z); o8[7] = (short)f2bf(f1.w);
        } else {
#pragma unroll
            for (int j = 0; j < 8; ++j) o8[j] = 0;
        }
        *(bf8*)(hb + (size_t)slab * ND128 + (size_t)cid * 8) = *(const bf8*)o8;
    }
}

// --- cast weights -> bf16 fragment order. blocks 0-3: WQ/WK/WV/WO (128x128),
// blocks 4-5: W2 (128x256) in two halves. -----------------------------------
__global__ __launch_bounds__(256) void k_cast_w(
    const float* __restrict__ WQ, const float* __restrict__ WK,
    const float* __restrict__ WV, const float* __restrict__ WO,
    const float* __restrict__ W2,
    short* __restrict__ Wqb, short* __restrict__ Wkb,
    short* __restrict__ Wvb, short* __restrict__ Wob, short* __restrict__ W2b)
{
    const int b = blockIdx.x;
    const float* Wsrc; short* dst; int K, base;
    if (b < 4) {
        Wsrc = b == 0 ? WQ : b == 1 ? WK : b == 2 ? WV : WO;
        dst  = b == 0 ? Wqb : b == 1 ? Wkb : b == 2 ? Wvb : Wob;
        K = 128; base = 0;
    } else {
        Wsrc = W2; dst = W2b; K = 256; base = (b - 4) * 2048;
    }
#pragma unroll
    for (int it = 0; it < 8; ++it) {
        int cid = base + it * 256 + threadIdx.x;
        int lane = cid & 63;
        int kb, nt;
        if (K == 128) { kb = (cid >> 6) & 3; nt = cid >> 8; }
        else          { kb = (cid >> 6) & 7; nt = cid >> 9; }
        int row = nt * 16 + (lane & 15);
        int col = kb * 32 + (lane >> 4) * 8;
        const float* p = Wsrc + (size_t)row * K + col;
        short o8[8];
#pragma unroll
        for (int j = 0; j < 8; ++j) o8[j] = (short)f2bf(p[j]);
        *(bf8*)(dst + (size_t)cid * 8) = *(const bf8*)o8;
    }
}

// --- QKV: out = hb @ Wb^T, bf16 row-major outputs.  grid (slabs, 3) --------
__global__ __launch_bounds__(256) void k_qkv(
    const short* __restrict__ hb, const short* __restrict__ Wqb,
    const short* __restrict__ Wkb, const short* __restrict__ Wvb,
    unsigned short* __restrict__ Qb, unsigned short* __restrict__ Kb,
    unsigned short* __restrict__ Vb, int N)
{
    const int slab = blockIdx.x;
    const int w = threadIdx.x >> 6, lane = threadIdx.x & 63;
    const short* __restrict__ Wb = blockIdx.y == 0 ? Wqb : blockIdx.y == 1 ? Wkb : Wvb;
    unsigned short* __restrict__ Ob = blockIdx.y == 0 ? Qb : blockIdx.y == 1 ? Kb : Vb;
    const short* A = hb + (size_t)slab * ND128;

    bf8 bfr[2][4];
#pragma unroll
    for (int nt = 0; nt < 2; ++nt)
#pragma unroll
        for (int kb = 0; kb < 4; ++kb)
            bfr[nt][kb] = *(const bf8*)(Wb + (size_t)(((2 * w + nt) * 4 + kb) * 64 + lane) * 8);

    f4 acc[8][2];
    f4 zero = {0.f, 0.f, 0.f, 0.f};
#pragma unroll
    for (int m = 0; m < 8; ++m) { acc[m][0] = zero; acc[m][1] = zero; }

#pragma unroll
    for (int m = 0; m < 8; ++m) {
        bf8 a0 = *(const bf8*)(A + (size_t)((0 * 8 + m) * 64 + lane) * 8);
        bf8 a1 = *(const bf8*)(A + (size_t)((1 * 8 + m) * 64 + lane) * 8);
        bf8 a2 = *(const bf8*)(A + (size_t)((2 * 8 + m) * 64 + lane) * 8);
        bf8 a3 = *(const bf8*)(A + (size_t)((3 * 8 + m) * 64 + lane) * 8);
        acc[m][0] = __builtin_amdgcn_mfma_f32_16x16x32_bf16(a0, bfr[0][0], acc[m][0], 0, 0, 0);
        acc[m][1] = __builtin_amdgcn_mfma_f32_16x16x32_bf16(a0, bfr[1][0], acc[m][1], 0, 0, 0);
        acc[m][0] = __builtin_amdgcn_mfma_f32_16x16x32_bf16(a1, bfr[0][1], acc[m][0], 0, 0, 0);
        acc[m][1] = __builtin_amdgcn_mfma_f32_16x16x32_bf16(a1, bfr[1][1], acc[m][1], 0, 0, 0);
        acc[m][0] = __builtin_amdgcn_mfma_f32_16x16x32_bf16(a2, bfr[0][2], acc[m][0], 0, 0, 0);
        acc[m][1] = __builtin_amdgcn_mfma_f32_16x16x32_bf16(a2, bfr[1][2], acc[m][1], 0, 0, 0);
        acc[m][0] = __builtin_amdgcn_mfma_f32_16x16x32_bf16(a3, bfr[0][3], acc[m][0], 0, 0, 0);
        acc[m][1] = __builtin_amdgcn_mfma_f32_16x16x32_bf16(a3, bfr[1][3], acc[m][1], 0, 0, 0);
    }

    const int c = lane & 15, quad = lane >> 4;
#pragma unroll
    for (int m = 0; m < 8; ++m)
#pragma unroll
        for (int nt = 0; nt < 2; ++nt) {
            int col = w * 32 + nt * 16 + c;
#pragma unroll
            for (int r = 0; r < 4; ++r) {
                int gr = slab * 128 + m * 16 + quad * 4 + r;
                if (gr < N) Ob[(size_t)gr * 128 + col] = f2bf(acc[m][nt][r]);
            }
        }
}

// --- CSR build -------------------------------------------------------------
__global__ __launch_bounds__(256) void k_hist(
    const int* __restrict__ dst, int* __restrict__ cursor, int E)
{
    int e = blockIdx.x * 256 + threadIdx.x;
    if (e < E) atomicAdd(&cursor[dst[e]], 1);
}

__global__ __launch_bounds__(1024) void k_scan(
    const int* cnt, int* rowptr, int* cursor, int N)
{
    __shared__ int part[1024];
    const int t = threadIdx.x;
    const int chunk = (N + 1023) >> 10;
    const int b0 = t * chunk;
    int lsum = 0;
    for (int i = 0; i < chunk; ++i) {
        int idx = b0 + i;
        if (idx < N) lsum += cnt[idx];
    }
    part[t] = lsum;
    __syncthreads();
    for (int off = 1; off < 1024; off <<= 1) {
        int v = (t >= off) ? part[t - off] : 0;
        __syncthreads();
        part[t] += v;
        __syncthreads();
    }
    int run = (t == 0) ? 0 : part[t - 1];
    for (int i = 0; i < chunk; ++i) {
        int idx = b0 + i;
        if (idx < N) {
            int cv = cnt[idx];
            rowptr[idx] = run;
            cursor[idx] = run;
            run += cv;
        }
    }
    if (t == 1023) rowptr[N] = part[1023];
}

__global__ __launch_bounds__(256) void k_scatter(
    const int* __restrict__ src, const int* __restrict__ dst,
    int* __restrict__ cursor, int* __restrict__ csr_src, int E)
{
    int e = blockIdx.x * 256 + threadIdx.x;
    if (e < E) {
        int pos = atomicAdd(&cursor[dst[e]], 1);
        csr_src[pos] = src[e];
    }
}

// --- attention: one wave per node, lane owns channels (2l, 2l+1). ----------
// Head = 16 channels = 8 lanes; dot via shfl_xor width 8. Output written
// directly in fragment order (becomes oproj's A operand).
__global__ __launch_bounds__(256) void k_attn(
    const unsigned short* __restrict__ Qb, const unsigned short* __restrict__ Kb,
    const unsigned short* __restrict__ Vb,
    const int* __restrict__ rowptr, const int* __restrict__ csr_src,
    unsigned short* __restrict__ attnf, int N)
{
    const int node = blockIdx.x * 4 + (threadIdx.x >> 6);
    const int lane = threadIdx.x & 63;
    if (node >= N) return;
    const int beg = rowptr[node], end = rowptr[node + 1];
    unsigned qq = ((const unsigned*)(Qb + (size_t)node * 128))[lane];
    const float qx = bf2f((unsigned short)(qq & 0xffff));
    const float qy = bf2f((unsigned short)(qq >> 16));
    float ax = 0.f, ay = 0.f, z = 0.f;
    int i = beg;
    for (; i + 1 < end; i += 2) {
        int s0 = csr_src[i], s1 = csr_src[i + 1];
        unsigned k0 = ((const unsigned*)(Kb + (size_t)s0 * 128))[lane];
        unsigned v0 = ((const unsigned*)(Vb + (size_t)s0 * 128))[lane];
        unsigned k1 = ((const unsigned*)(Kb + (size_t)s1 * 128))[lane];
        unsigned v1 = ((const unsigned*)(Vb + (size_t)s1 * 128))[lane];
        float p0 = qx * bf2f((unsigned short)(k0 & 0xffff)) + qy * bf2f((unsigned short)(k0 >> 16));
        float p1 = qx * bf2f((unsigned short)(k1 & 0xffff)) + qy * bf2f((unsigned short)(k1 >> 16));
        p0 += __shfl_xor(p0, 4, 8); p0 += __shfl_xor(p0, 2, 8); p0 += __shfl_xor(p0, 1, 8);
        p1 += __shfl_xor(p1, 4, 8); p1 += __shfl_xor(p1, 2, 8); p1 += __shfl_xor(p1, 1, 8);
        float sc0 = __expf(fminf(fmaxf(p0 * 0.25f, -5.f), 5.f));
        float sc1 = __expf(fminf(fmaxf(p1 * 0.25f, -5.f), 5.f));
        ax = fmaf(bf2f((unsigned short)(v0 & 0xffff)), sc0, ax);
        ay = fmaf(bf2f((unsigned short)(v0 >> 16)), sc0, ay);
        ax = fmaf(bf2f((unsigned short)(v1 & 0xffff)), sc1, ax);
        ay = fmaf(bf2f((unsigned short)(v1 >> 16)), sc1, ay);
        z += sc0 + sc1;
    }
    if (i < end) {
        int s0 = csr_src[i];
        unsigned k0 = ((const unsigned*)(Kb + (size_t)s0 * 128))[lane];
        unsigned v0 = ((const unsigned*)(Vb + (size_t)s0 * 128))[lane];
        float p0 = qx * bf2f((unsigned short)(k0 & 0xffff)) + qy * bf2f((unsigned short)(k0 >> 16));
        p0 += __shfl_xor(p0, 4, 8); p0 += __shfl_xor(p0, 2, 8); p0 += __shfl_xor(p0, 1, 8);
        float sc0 = __expf(fminf(fmaxf(p0 * 0.25f, -5.f), 5.f));
        ax = fmaf(bf2f((unsigned short)(v0 & 0xffff)), sc0, ax);
        ay = fmaf(bf2f((unsigned short)(v0 >> 16)), sc0, ay);
        z += sc0;
    }
    float inv = 1.f / z;
    ax *= inv; ay *= inv;
    int slab = node >> 7, m = (node >> 4) & 7, lr = node & 15;
    int kb = lane >> 4, quad2 = (lane & 15) >> 2, j = (lane & 3) * 2;
    unsigned outw = ((unsigned)f2bf(ay) << 16) | (unsigned)f2bf(ax);
    *(unsigned*)(attnf + (size_t)slab * ND128 +
                 (size_t)(((kb * 8 + m) * 64 + lr + 16 * quad2) * 8 + j)) = outw;
}

// --- O-proj: t1 = attn @ WO^T + h + bO.  Writes t1 fp32 (d_out) AND bf16
// fragment order (t1b), accumulates BN1 column sums. ------------------------
__global__ __launch_bounds__(256) void k_oproj(
    const short* __restrict__ attnf, const short* __restrict__ Wob,
    const float* __restrict__ h, const float* __restrict__ bO,
    float* __restrict__ out, short* __restrict__ t1b,
    float* __restrict__ bn, int N)
{
    __shared__ float csum[128], csq[128];
    const int tid = threadIdx.x, slab = blockIdx.x;
    const int w = tid >> 6, lane = tid & 63;
    if (tid < 128) { csum[tid] = 0.f; csq[tid] = 0.f; }
    __syncthreads();
    const short* A = attnf + (size_t)slab * ND128;

    bf8 bfr[2][4];
#pragma unroll
    for (int nt = 0; nt < 2; ++nt)
#pragma unroll
        for (int kb = 0; kb < 4; ++kb)
            bfr[nt][kb] = *(const bf8*)(Wob + (size_t)(((2 * w + nt) * 4 + kb) * 64 + lane) * 8);

    f4 acc[8][2];
    f4 zero = {0.f, 0.f, 0.f, 0.f};
#pragma unroll
    for (int m = 0; m < 8; ++m) { acc[m][0] = zero; acc[m][1] = zero; }
#pragma unroll
    for (int m = 0; m < 8; ++m) {
#pragma unroll
        for (int kb = 0; kb < 4; ++kb) {
            bf8 a = *(const bf8*)(A + (size_t)((kb * 8 + m) * 64 + lane) * 8);
            acc[m][0] = __builtin_amdgcn_mfma_f32_16x16x32_bf16(a, bfr[0][kb], acc[m][0], 0, 0, 0);
            acc[m][1] = __builtin_amdgcn_mfma_f32_16x16x32_bf16(a, bfr[1][kb], acc[m][1], 0, 0, 0);
        }
    }

    const int c = lane & 15, quad = lane >> 4;
    float pcs[2] = {0.f, 0.f}, pcq[2] = {0.f, 0.f};
#pragma unroll
    for (int m = 0; m < 8; ++m)
#pragma unroll
        for (int nt = 0; nt < 2; ++nt) {
            int cl = w * 32 + nt * 16 + c;
            float bo = bO[cl];
            int quad2 = nt * 2 + (c >> 3), j = c & 7;
#pragma unroll
            for (int r = 0; r < 4; ++r) {
                int rl = m * 16 + quad * 4 + r;
                int gr = slab * 128 + rl;
                if (gr < N) {
                    float v = acc[m][nt][r] + h[(size_t)gr * 128 + cl] + bo;
                    out[(size_t)gr * 128 + cl] = v;
                    t1b[(size_t)slab * ND128 +
                        (size_t)(((w * 8 + m) * 64 + quad * 4 + r + 16 * quad2) * 8 + j)] =
                        (short)f2bf(v);
                    pcs[nt] += v; pcq[nt] += v * v;
                }
            }
        }
#pragma unroll
    for (int nt = 0; nt < 2; ++nt) {
        atomicAdd(&csum[w * 32 + nt * 16 + c], pcs[nt]);
        atomicAdd(&csq[w * 32 + nt * 16 + c], pcq[nt]);
    }
    __syncthreads();
    if (tid < 128) {
        atomicAdd(bn + tid, csum[tid]);
        atomicAdd(bn + 128 + tid, csq[tid]);
    }
}

// --- fold BN1 into W1/bias: s=g/sqrt(var+eps), b=bb1-mu*s;
// W1b[o][i] = bf16(W1[o][i]*s[i]); badj[o] = b1[o] + sum_i W1[o][i]*b[i].
__global__ __launch_bounds__(256) void k_fold1(
    const float* __restrict__ bn, const float* __restrict__ g1,
    const float* __restrict__ bb1, const float* __restrict__ W1,
    const float* __restrict__ b1, short* __restrict__ W1b,
    float* __restrict__ badj, float* __restrict__ sfold,
    float* __restrict__ bfold, int N)
{
    __shared__ float s1s[128], b1s[128];
    const int tid = threadIdx.x;
    if (tid < 128) {
        float invN = 1.f / (float)N;
        float mu = bn[tid] * invN;
        float var = bn[128 + tid] * invN - mu * mu;
        float s = g1[tid] * rsqrtf(var + 1e-5f);
        s1s[tid] = s; b1s[tid] = bb1[tid] - mu * s;
        sfold[tid] = s; bfold[tid] = b1s[tid];
    }
    __syncthreads();
    const int o = tid;
    float bsum = b1[o];
    const int nt = o >> 4, lanelow = o & 15;
    for (int i2 = 0; i2 < 128; ++i2) {
        float wv = W1[(size_t)o * 128 + i2];
        bsum = fmaf(wv, b1s[i2], bsum);
        int kb = i2 >> 5, quad = (i2 >> 3) & 3, j = i2 & 7;
        W1b[(size_t)(((nt * 4 + kb) * 64 + lanelow + 16 * quad) * 8 + j)] =
            (short)f2bf(wv * s1s[i2]);
    }
    badj[o] = bsum;
}

// --- FFN1: u = relu(t1b @ W1s^T + badj), output bf16 frag order (K=256
// layout for ffn2).  grid (slabs, 2): col halves. ---------------------------
__global__ __launch_bounds__(256) void k_ffn1(
    const short* __restrict__ t1b, const short* __restrict__ W1b,
    const float* __restrict__ badj, short* __restrict__ ub, int N)
{
    const int slab = blockIdx.x, ch = blockIdx.y;
    const int w = threadIdx.x >> 6, lane = threadIdx.x & 63;
    const short* A = t1b + (size_t)slab * ND128;

    bf8 bfr[2][4];
#pragma unroll
    for (int nt = 0; nt < 2; ++nt)
#pragma unroll
        for (int kb = 0; kb < 4; ++kb) {
            int ntg = ch * 8 + 2 * w + nt;
            bfr[nt][kb] = *(const bf8*)(W1b + (size_t)((ntg * 4 + kb) * 64 + lane) * 8);
        }

    f4 acc[8][2];
    f4 zero = {0.f, 0.f, 0.f, 0.f};
#pragma unroll
    for (int m = 0; m < 8; ++m) { acc[m][0] = zero; acc[m][1] = zero; }
#pragma unroll
    for (int m = 0; m < 8; ++m) {
#pragma unroll
        for (int kb = 0; kb < 4; ++kb) {
            bf8 a = *(const bf8*)(A + (size_t)((kb * 8 + m) * 64 + lane) * 8);
            acc[m][0] = __builtin_amdgcn_mfma_f32_16x16x32_bf16(a, bfr[0][kb], acc[m][0], 0, 0, 0);
            acc[m][1] = __builtin_amdgcn_mfma_f32_16x16x32_bf16(a, bfr[1][kb], acc[m][1], 0, 0, 0);
        }
    }

    const int c = lane & 15, quad = lane >> 4;
    const int kbu = ch * 4 + w;
#pragma unroll
    for (int m = 0; m < 8; ++m)
#pragma unroll
        for (int nt = 0; nt < 2; ++nt) {
            int colg = ch * 128 + w * 32 + nt * 16 + c;
            float ba = badj[colg];
            int quad2 = nt * 2 + (c >> 3), j = c & 7;
#pragma unroll
            for (int r = 0; r < 4; ++r) {
                int gr = slab * 128 + m * 16 + quad * 4 + r;
                if (gr < N) {
                    float v = fmaxf(acc[m][nt][r] + ba, 0.f);
                    ub[(size_t)slab * 32768 +
                       (size_t)(((kbu * 8 + m) * 64 + quad * 4 + r + 16 * quad2) * 8 + j)] =
                        (short)f2bf(v);
                }
            }
        }
}

// --- FFN2: t2 = (s1*t1 + b1v) + u @ W2^T + b2, in place on d_out (holds t1
// fp32); accumulates BN2 sums. ----------------------------------------------
__global__ __launch_bounds__(256) void k_ffn2(
    const short* __restrict__ ub, const short* __restrict__ W2b,
    const float* __restrict__ sfold, const float* __restrict__ bfold,
    const float* __restrict__ b2, float* __restrict__ out,
    float* __restrict__ bn, int N)
{
    __shared__ float csum[128], csq[128], sS[128], sB[128];
    const int tid = threadIdx.x, slab = blockIdx.x;
    const int w = tid >> 6, lane = tid & 63;
    if (tid < 128) {
        csum[tid] = 0.f; csq[tid] = 0.f;
        sS[tid] = sfold[tid]; sB[tid] = bfold[tid] + b2[tid];
    }
    __syncthreads();
    const short* A = ub + (size_t)slab * 32768;

    bf8 bfr[2][8];
#pragma unroll
    for (int nt = 0; nt < 2; ++nt)
#pragma unroll
        for (int kb = 0; kb < 8; ++kb)
            bfr[nt][kb] = *(const bf8*)(W2b + (size_t)(((2 * w + nt) * 8 + kb) * 64 + lane) * 8);

    f4 acc[8][2];
    f4 zero = {0.f, 0.f, 0.f, 0.f};
#pragma unroll
    for (int m = 0; m < 8; ++m) { acc[m][0] = zero; acc[m][1] = zero; }
#pragma unroll
    for (int m = 0; m < 8; ++m) {
#pragma unroll
        for (int kb = 0; kb < 8; ++kb) {
            bf8 a = *(const bf8*)(A + (size_t)((kb * 8 + m) * 64 + lane) * 8);
            acc[m][0] = __builtin_amdgcn_mfma_f32_16x16x32_bf16(a, bfr[0][kb], acc[m][0], 0, 0, 0);
            acc[m][1] = __builtin_amdgcn_mfma_f32_16x16x32_bf16(a, bfr[1][kb], acc[m][1], 0, 0, 0);
        }
    }

    const int c = lane & 15, quad = lane >> 4;
    float pcs[2] = {0.f, 0.f}, pcq[2] = {0.f, 0.f};
#pragma unroll
    for (int m = 0; m < 8; ++m)
#pragma unroll
        for (int nt = 0; nt < 2; ++nt) {
            int cl = w * 32 + nt * 16 + c;
            float ss = sS[cl], sb = sB[cl];
#pragma unroll
            for (int r = 0; r < 4; ++r) {
                int gr = slab * 128 + m * 16 + quad * 4 + r;
                if (gr < N) {
                    size_t gi = (size_t)gr * 128 + cl;
                    float v = acc[m][nt][r] + fmaf(ss, out[gi], sb);
                    out[gi] = v;
                    pcs[nt] += v; pcq[nt] += v * v;
                }
            }
        }
#pragma unroll
    for (int nt = 0; nt < 2; ++nt) {
        atomicAdd(&csum[w * 32 + nt * 16 + c], pcs[nt]);
        atomicAdd(&csq[w * 32 + nt * 16 + c], pcq[nt]);
    }
    __syncthreads();
    if (tid < 128) {
        atomicAdd(bn + 256 + tid, csum[tid]);
        atomicAdd(bn + 384 + tid, csq[tid]);
    }
}

// --- BN2 normalize in place ------------------------------------------------
__global__ __launch_bounds__(256) void k_bn2(
    float* __restrict__ out, const float* __restrict__ bn,
    const float* __restrict__ g2, const float* __restrict__ bb2, int N)
{
    __shared__ float sS[128], sB[128];
    const int tid = threadIdx.x;
    if (tid < 128) {
        float invN = 1.f / (float)N;
        float mu = bn[256 + tid] * invN;
        float var = bn[384 + tid] * invN - mu * mu;
        float scl = g2[tid] * rsqrtf(var + 1e-5f);
        sS[tid] = scl;
        sB[tid] = bb2[tid] - mu * scl;
    }
    __syncthreads();
    size_t idx = (size_t)blockIdx.x * 256 + tid;
    size_t total = (size_t)N * 32;
    if (idx < total) {
        int c0 = (int)((idx * 4) & 127);
        float4 v = *(const float4*)(out + idx * 4);
        v.x = fmaf(v.x, sS[c0 + 0], sB[c0 + 0]);
        v.y = fmaf(v.y, sS[c0 + 1], sB[c0 + 1]);
        v.z = fmaf(v.z, sS[c0 + 2], sB[c0 + 2]);
        v.w = fmaf(v.w, sS[c0 + 3], sB[c0 + 3]);
        *(float4*)(out + idx * 4) = v;
    }
}

extern "C" void kernel_launch(void* const* d_in, const int* in_sizes, int n_in,
                              void* d_out, int out_size, void* d_ws, size_t ws_size,
                              hipStream_t stream)
{
    const float* h   = (const float*)d_in[0];
    const int*   src = (const int*)d_in[1];
    const int*   dst = (const int*)d_in[2];
    const float* WQ  = (const float*)d_in[3];
    const float* WK  = (const float*)d_in[4];
    const float* WV  = (const float*)d_in[5];
    const float* WO  = (const float*)d_in[6];
    const float* bO  = (const float*)d_in[7];
    const float* W1  = (const float*)d_in[8];
    const float* b1  = (const float*)d_in[9];
    const float* W2  = (const float*)d_in[10];
    const float* b2  = (const float*)d_in[11];
    const float* g1  = (const float*)d_in[12];
    const float* bb1 = (const float*)d_in[13];
    const float* g2  = (const float*)d_in[14];
    const float* bb2 = (const float*)d_in[15];
    float* out = (float*)d_out;

    const int N = in_sizes[0] / 128;
    const int E = in_sizes[1];
    const int slabs = (N + 127) / 128;
    const size_t B1 = (size_t)slabs * 32768;   // bytes of one bf16 N_pad x 128 buffer

    char* Wp = (char*)d_ws;
    short* hb  = (short*)Wp;                         // -> attnf after qkv
    unsigned short* Qb = (unsigned short*)(Wp + B1);
    unsigned short* Kb = (unsigned short*)(Wp + 2 * B1);
    unsigned short* Vb = (unsigned short*)(Wp + 3 * B1);
    short* t1b = (short*)(Wp + 3 * B1);              // overlays Vb (dead after attn)
    short* ub  = (short*)(Wp + B1);                  // overlays Qb+Kb (dead after attn)
    const size_t base = 4 * B1;
    short* Wqb = (short*)(Wp + base);
    short* Wkb = (short*)(Wp + base + 32768);
    short* Wvb = (short*)(Wp + base + 65536);
    short* Wob = (short*)(Wp + base + 98304);
    short* W1b = (short*)(Wp + base + 131072);
    short* W2b = (short*)(Wp + base + 196608);
    float* badj  = (float*)(Wp + base + 262144);
    float* sfold = (float*)(Wp + base + 263168);
    float* bfold = (float*)(Wp + base + 263680);
    float* bn    = (float*)(Wp + base + 264192);     // 512 floats, zeroed
    int* cursor  = (int*)(Wp + base + 266240);       // N ints, zeroed (contig w/ bn)
    int* rowptr  = (int*)(Wp + base + 266240 + (size_t)N * 4);
    int* csr     = (int*)(Wp + base + 266240 + (size_t)N * 8 + 8);

    hipMemsetAsync(bn, 0, 2048 + (size_t)N * 4, stream);

    k_cast_h<<<slabs, 256, 0, stream>>>(h, hb, N);
    k_cast_w<<<6, 256, 0, stream>>>(WQ, WK, WV, WO, W2, Wqb, Wkb, Wvb, Wob, W2b);
    k_qkv<<<dim3(slabs, 3), 256, 0, stream>>>(hb, Wqb, Wkb, Wvb, Qb, Kb, Vb, N);
    k_hist<<<(E + 255) / 256, 256, 0, stream>>>(dst, cursor, E);
    k_scan<<<1, 1024, 0, stream>>>(cursor, rowptr, cursor, N);
    k_scatter<<<(E + 255) / 256, 256, 0, stream>>>(src, dst, cursor, csr, E);
    k_attn<<<(N + 3) / 4, 256, 0, stream>>>(Qb, Kb, Vb, rowptr, csr,
                                            (unsigned short*)hb, N);
    k_oproj<<<slabs, 256, 0, stream>>>((const short*)hb, Wob, h, bO, out, t1b, bn, N);
    k_fold1<<<1, 256, 0, stream>>>(bn, g1, bb1, W1, b1, W1b, badj, sfold, bfold, N);
    k_ffn1<<<dim3(slabs, 2), 256, 0, stream>>>(t1b, W1b, badj, ub, N);
    k_ffn2<<<slabs, 256, 0, stream>>>(ub, W2b, sfold, bfold, b2, out, bn, N);
    k_bn2<<<(int)(((size_t)N * 32 + 255) / 256), 256, 0, stream>>>(out, bn, g2, bb2, N);
}

// Round 4
// 376.996 us; speedup vs baseline: 14.1861x; 1.2923x over previous
//
#include <hip/hip_runtime.h>
#include <math.h>

// ---------------------------------------------------------------------------
// GraphTransformerLayer N=50000, E=640000, D=128, H=8, DH=16  (gfx950)
// Round 4: round-3 pipeline (bf16 MFMA GEMMs, fragment-ordered layouts,
// bf16 gather attention, BN1 folded into W1) + hierarchical 3-pass CSR scan
// replacing the 127 us single-block scan.
//
// Fragment order for an MxK slab (M=128, K=KB*32):
//   elem index = ((kb*8 + mtile)*64 + lane)*8 + j
//   row = mtile*16 + (lane&15),  col = kb*32 + (lane>>4)*8 + j
// MFMA 16x16x32 bf16: A[m=lane&15][k=(lane>>4)*8+j]; C/D: col=lane&15,
// row=(lane>>4)*4+reg.
// ---------------------------------------------------------------------------

#define ND128 16384
typedef __attribute__((ext_vector_type(8))) short bf8;
typedef __attribute__((ext_vector_type(4))) float f4;

__device__ __forceinline__ unsigned short f2bf(float f) {
    unsigned x = __float_as_uint(f);
    unsigned r = (x + 0x7fffu + ((x >> 16) & 1u)) >> 16;
    return (unsigned short)r;
}
__device__ __forceinline__ float bf2f(unsigned short u) {
    return __uint_as_float(((unsigned)u) << 16);
}

// --- cast h (fp32 row-major) -> hb (bf16 fragment order, zero-padded rows) --
__global__ __launch_bounds__(256) void k_cast_h(
    const float* __restrict__ h, short* __restrict__ hb, int N)
{
    const int slab = blockIdx.x;
    const int tid = threadIdx.x;
#pragma unroll
    for (int it = 0; it < 8; ++it) {
        int cid = it * 256 + tid;              // 0..2047
        int lane = cid & 63;
        int m = (cid >> 6) & 7;
        int kb = cid >> 9;
        int row = slab * 128 + m * 16 + (lane & 15);
        int col = kb * 32 + (lane >> 4) * 8;
        short o8[8];
        if (row < N) {
            const float* p = h + (size_t)row * 128 + col;
            float4 f0 = *(const float4*)p;
            float4 f1 = *(const float4*)(p + 4);
            o8[0] = (short)f2bf(f0.x); o8[1] = (short)f2bf(f0.y);
            o8[2] = (short)f2bf(f0.z); o8[3] = (short)f2bf(f0.w);
            o8[4] = (short)f2bf(f1.x); o8[5] = (short)f2bf(f1.y);
            o8[6] = (short)f2bf(f1.z); o8[7] = (short)f2bf(f1.w);
        } else {
#pragma unroll
            for (int j = 0; j < 8; ++j) o8[j] = 0;
        }
        *(bf8*)(hb + (size_t)slab * ND128 + (size_t)cid * 8) = *(const bf8*)o8;
    }
}

// --- cast weights -> bf16 fragment order. blocks 0-3: WQ/WK/WV/WO (128x128),
// blocks 4-5: W2 (128x256) in two halves. -----------------------------------
__global__ __launch_bounds__(256) void k_cast_w(
    const float* __restrict__ WQ, const float* __restrict__ WK,
    const float* __restrict__ WV, const float* __restrict__ WO,
    const float* __restrict__ W2,
    short* __restrict__ Wqb, short* __restrict__ Wkb,
    short* __restrict__ Wvb, short* __restrict__ Wob, short* __restrict__ W2b)
{
    const int b = blockIdx.x;
    const float* Wsrc; short* dst; int K, base;
    if (b < 4) {
        Wsrc = b == 0 ? WQ : b == 1 ? WK : b == 2 ? WV : WO;
        dst  = b == 0 ? Wqb : b == 1 ? Wkb : b == 2 ? Wvb : Wob;
        K = 128; base = 0;
    } else {
        Wsrc = W2; dst = W2b; K = 256; base = (b - 4) * 2048;
    }
#pragma unroll
    for (int it = 0; it < 8; ++it) {
        int cid = base + it * 256 + threadIdx.x;
        int lane = cid & 63;
        int kb, nt;
        if (K == 128) { kb = (cid >> 6) & 3; nt = cid >> 8; }
        else          { kb = (cid >> 6) & 7; nt = cid >> 9; }
        int row = nt * 16 + (lane & 15);
        int col = kb * 32 + (lane >> 4) * 8;
        const float* p = Wsrc + (size_t)row * K + col;
        short o8[8];
#pragma unroll
        for (int j = 0; j < 8; ++j) o8[j] = (short)f2bf(p[j]);
        *(bf8*)(dst + (size_t)cid * 8) = *(const bf8*)o8;
    }
}

// --- QKV: out = hb @ Wb^T, bf16 row-major outputs.  grid (slabs, 3) --------
__global__ __launch_bounds__(256) void k_qkv(
    const short* __restrict__ hb, const short* __restrict__ Wqb,
    const short* __restrict__ Wkb, const short* __restrict__ Wvb,
    unsigned short* __restrict__ Qb, unsigned short* __restrict__ Kb,
    unsigned short* __restrict__ Vb, int N)
{
    const int slab = blockIdx.x;
    const int w = threadIdx.x >> 6, lane = threadIdx.x & 63;
    const short* __restrict__ Wb = blockIdx.y == 0 ? Wqb : blockIdx.y == 1 ? Wkb : Wvb;
    unsigned short* __restrict__ Ob = blockIdx.y == 0 ? Qb : blockIdx.y == 1 ? Kb : Vb;
    const short* A = hb + (size_t)slab * ND128;

    bf8 bfr[2][4];
#pragma unroll
    for (int nt = 0; nt < 2; ++nt)
#pragma unroll
        for (int kb = 0; kb < 4; ++kb)
            bfr[nt][kb] = *(const bf8*)(Wb + (size_t)(((2 * w + nt) * 4 + kb) * 64 + lane) * 8);

    f4 acc[8][2];
    f4 zero = {0.f, 0.f, 0.f, 0.f};
#pragma unroll
    for (int m = 0; m < 8; ++m) { acc[m][0] = zero; acc[m][1] = zero; }

#pragma unroll
    for (int m = 0; m < 8; ++m) {
        bf8 a0 = *(const bf8*)(A + (size_t)((0 * 8 + m) * 64 + lane) * 8);
        bf8 a1 = *(const bf8*)(A + (size_t)((1 * 8 + m) * 64 + lane) * 8);
        bf8 a2 = *(const bf8*)(A + (size_t)((2 * 8 + m) * 64 + lane) * 8);
        bf8 a3 = *(const bf8*)(A + (size_t)((3 * 8 + m) * 64 + lane) * 8);
        acc[m][0] = __builtin_amdgcn_mfma_f32_16x16x32_bf16(a0, bfr[0][0], acc[m][0], 0, 0, 0);
        acc[m][1] = __builtin_amdgcn_mfma_f32_16x16x32_bf16(a0, bfr[1][0], acc[m][1], 0, 0, 0);
        acc[m][0] = __builtin_amdgcn_mfma_f32_16x16x32_bf16(a1, bfr[0][1], acc[m][0], 0, 0, 0);
        acc[m][1] = __builtin_amdgcn_mfma_f32_16x16x32_bf16(a1, bfr[1][1], acc[m][1], 0, 0, 0);
        acc[m][0] = __builtin_amdgcn_mfma_f32_16x16x32_bf16(a2, bfr[0][2], acc[m][0], 0, 0, 0);
        acc[m][1] = __builtin_amdgcn_mfma_f32_16x16x32_bf16(a2, bfr[1][2], acc[m][1], 0, 0, 0);
        acc[m][0] = __builtin_amdgcn_mfma_f32_16x16x32_bf16(a3, bfr[0][3], acc[m][0], 0, 0, 0);
        acc[m][1] = __builtin_amdgcn_mfma_f32_16x16x32_bf16(a3, bfr[1][3], acc[m][1], 0, 0, 0);
    }

    const int c = lane & 15, quad = lane >> 4;
#pragma unroll
    for (int m = 0; m < 8; ++m)
#pragma unroll
        for (int nt = 0; nt < 2; ++nt) {
            int col = w * 32 + nt * 16 + c;
#pragma unroll
            for (int r = 0; r < 4; ++r) {
                int gr = slab * 128 + m * 16 + quad * 4 + r;
                if (gr < N) Ob[(size_t)gr * 128 + col] = f2bf(acc[m][nt][r]);
            }
        }
}

// --- CSR build -------------------------------------------------------------
__global__ __launch_bounds__(256) void k_hist(
    const int* __restrict__ dst, int* __restrict__ cursor, int E)
{
    int e = blockIdx.x * 256 + threadIdx.x;
    if (e < E) atomicAdd(&cursor[dst[e]], 1);
}

// Hierarchical scan, 2048 elems per block.
// Pass A: per-block totals via wave-shuffle reduce.
__global__ __launch_bounds__(256) void k_scanA(
    const int* __restrict__ cnt, int* __restrict__ bsum, int N)
{
    const int t = threadIdx.x;
    int base = blockIdx.x * 2048 + t * 8;
    int s = 0;
#pragma unroll
    for (int j = 0; j < 8; ++j) {
        int idx = base + j;
        if (idx < N) s += cnt[idx];
    }
#pragma unroll
    for (int off = 32; off; off >>= 1) s += __shfl_down(s, off, 64);
    __shared__ int ws4[4];
    if ((t & 63) == 0) ws4[t >> 6] = s;
    __syncthreads();
    if (t == 0) bsum[blockIdx.x] = ws4[0] + ws4[1] + ws4[2] + ws4[3];
}

// Pass B: tiny sequential scan of block sums (nb ~ 25); writes rowptr[N].
__global__ void k_scanB(
    const int* __restrict__ bsum, int* __restrict__ boff,
    int* __restrict__ rowptrN, int nb)
{
    if (threadIdx.x == 0) {
        int run = 0;
        for (int i = 0; i < nb; ++i) { boff[i] = run; run += bsum[i]; }
        *rowptrN = run;
    }
}

// Pass C: block-local exclusive scan + block offset -> rowptr & cursor.
// cnt aliases cursor: each block reads its own range fully before writing it.
__global__ __launch_bounds__(256) void k_scanC(
    const int* __restrict__ cnt, const int* __restrict__ boff,
    int* __restrict__ rowptr, int* __restrict__ cursor, int N)
{
    const int t = threadIdx.x;
    int base = blockIdx.x * 2048 + t * 8;
    int loc[8];
    int s = 0;
#pragma unroll
    for (int j = 0; j < 8; ++j) {
        int idx = base + j;
        loc[j] = (idx < N) ? cnt[idx] : 0;
        s += loc[j];
    }
    __shared__ int part[256];
    part[t] = s;
    __syncthreads();
    for (int off = 1; off < 256; off <<= 1) {
        int v = (t >= off) ? part[t - off] : 0;
        __syncthreads();
        part[t] += v;
        __syncthreads();
    }
    int run = boff[blockIdx.x] + (t ? part[t - 1] : 0);
#pragma unroll
    for (int j = 0; j < 8; ++j) {
        int idx = base + j;
        if (idx < N) { rowptr[idx] = run; cursor[idx] = run; run += loc[j]; }
    }
}

__global__ __launch_bounds__(256) void k_scatter(
    const int* __restrict__ src, const int* __restrict__ dst,
    int* __restrict__ cursor, int* __restrict__ csr_src, int E)
{
    int e = blockIdx.x * 256 + threadIdx.x;
    if (e < E) {
        int pos = atomicAdd(&cursor[dst[e]], 1);
        csr_src[pos] = src[e];
    }
}

// --- attention: one wave per node, lane owns channels (2l, 2l+1). ----------
__global__ __launch_bounds__(256) void k_attn(
    const unsigned short* __restrict__ Qb, const unsigned short* __restrict__ Kb,
    const unsigned short* __restrict__ Vb,
    const int* __restrict__ rowptr, const int* __restrict__ csr_src,
    unsigned short* __restrict__ attnf, int N)
{
    const int node = blockIdx.x * 4 + (threadIdx.x >> 6);
    const int lane = threadIdx.x & 63;
    if (node >= N) return;
    const int beg = rowptr[node], end = rowptr[node + 1];
    unsigned qq = ((const unsigned*)(Qb + (size_t)node * 128))[lane];
    const float qx = bf2f((unsigned short)(qq & 0xffff));
    const float qy = bf2f((unsigned short)(qq >> 16));
    float ax = 0.f, ay = 0.f, z = 0.f;
    int i = beg;
    for (; i + 1 < end; i += 2) {
        int s0 = csr_src[i], s1 = csr_src[i + 1];
        unsigned k0 = ((const unsigned*)(Kb + (size_t)s0 * 128))[lane];
        unsigned v0 = ((const unsigned*)(Vb + (size_t)s0 * 128))[lane];
        unsigned k1 = ((const unsigned*)(Kb + (size_t)s1 * 128))[lane];
        unsigned v1 = ((const unsigned*)(Vb + (size_t)s1 * 128))[lane];
        float p0 = qx * bf2f((unsigned short)(k0 & 0xffff)) + qy * bf2f((unsigned short)(k0 >> 16));
        float p1 = qx * bf2f((unsigned short)(k1 & 0xffff)) + qy * bf2f((unsigned short)(k1 >> 16));
        p0 += __shfl_xor(p0, 4, 8); p0 += __shfl_xor(p0, 2, 8); p0 += __shfl_xor(p0, 1, 8);
        p1 += __shfl_xor(p1, 4, 8); p1 += __shfl_xor(p1, 2, 8); p1 += __shfl_xor(p1, 1, 8);
        float sc0 = __expf(fminf(fmaxf(p0 * 0.25f, -5.f), 5.f));
        float sc1 = __expf(fminf(fmaxf(p1 * 0.25f, -5.f), 5.f));
        ax = fmaf(bf2f((unsigned short)(v0 & 0xffff)), sc0, ax);
        ay = fmaf(bf2f((unsigned short)(v0 >> 16)), sc0, ay);
        ax = fmaf(bf2f((unsigned short)(v1 & 0xffff)), sc1, ax);
        ay = fmaf(bf2f((unsigned short)(v1 >> 16)), sc1, ay);
        z += sc0 + sc1;
    }
    if (i < end) {
        int s0 = csr_src[i];
        unsigned k0 = ((const unsigned*)(Kb + (size_t)s0 * 128))[lane];
        unsigned v0 = ((const unsigned*)(Vb + (size_t)s0 * 128))[lane];
        float p0 = qx * bf2f((unsigned short)(k0 & 0xffff)) + qy * bf2f((unsigned short)(k0 >> 16));
        p0 += __shfl_xor(p0, 4, 8); p0 += __shfl_xor(p0, 2, 8); p0 += __shfl_xor(p0, 1, 8);
        float sc0 = __expf(fminf(fmaxf(p0 * 0.25f, -5.f), 5.f));
        ax = fmaf(bf2f((unsigned short)(v0 & 0xffff)), sc0, ax);
        ay = fmaf(bf2f((unsigned short)(v0 >> 16)), sc0, ay);
        z += sc0;
    }
    float inv = 1.f / z;
    ax *= inv; ay *= inv;
    int slab = node >> 7, m = (node >> 4) & 7, lr = node & 15;
    int kb = lane >> 4, quad2 = (lane & 15) >> 2, j = (lane & 3) * 2;
    unsigned outw = ((unsigned)f2bf(ay) << 16) | (unsigned)f2bf(ax);
    *(unsigned*)(attnf + (size_t)slab * ND128 +
                 (size_t)(((kb * 8 + m) * 64 + lr + 16 * quad2) * 8 + j)) = outw;
}

// --- O-proj: t1 = attn @ WO^T + h + bO. fp32 out + bf16 frag t1b + BN1 sums.
__global__ __launch_bounds__(256) void k_oproj(
    const short* __restrict__ attnf, const short* __restrict__ Wob,
    const float* __restrict__ h, const float* __restrict__ bO,
    float* __restrict__ out, short* __restrict__ t1b,
    float* __restrict__ bn, int N)
{
    __shared__ float csum[128], csq[128];
    const int tid = threadIdx.x, slab = blockIdx.x;
    const int w = tid >> 6, lane = tid & 63;
    if (tid < 128) { csum[tid] = 0.f; csq[tid] = 0.f; }
    __syncthreads();
    const short* A = attnf + (size_t)slab * ND128;

    bf8 bfr[2][4];
#pragma unroll
    for (int nt = 0; nt < 2; ++nt)
#pragma unroll
        for (int kb = 0; kb < 4; ++kb)
            bfr[nt][kb] = *(const bf8*)(Wob + (size_t)(((2 * w + nt) * 4 + kb) * 64 + lane) * 8);

    f4 acc[8][2];
    f4 zero = {0.f, 0.f, 0.f, 0.f};
#pragma unroll
    for (int m = 0; m < 8; ++m) { acc[m][0] = zero; acc[m][1] = zero; }
#pragma unroll
    for (int m = 0; m < 8; ++m) {
#pragma unroll
        for (int kb = 0; kb < 4; ++kb) {
            bf8 a = *(const bf8*)(A + (size_t)((kb * 8 + m) * 64 + lane) * 8);
            acc[m][0] = __builtin_amdgcn_mfma_f32_16x16x32_bf16(a, bfr[0][kb], acc[m][0], 0, 0, 0);
            acc[m][1] = __builtin_amdgcn_mfma_f32_16x16x32_bf16(a, bfr[1][kb], acc[m][1], 0, 0, 0);
        }
    }

    const int c = lane & 15, quad = lane >> 4;
    float pcs[2] = {0.f, 0.f}, pcq[2] = {0.f, 0.f};
#pragma unroll
    for (int m = 0; m < 8; ++m)
#pragma unroll
        for (int nt = 0; nt < 2; ++nt) {
            int cl = w * 32 + nt * 16 + c;
            float bo = bO[cl];
            int quad2 = nt * 2 + (c >> 3), j = c & 7;
#pragma unroll
            for (int r = 0; r < 4; ++r) {
                int rl = m * 16 + quad * 4 + r;
                int gr = slab * 128 + rl;
                if (gr < N) {
                    float v = acc[m][nt][r] + h[(size_t)gr * 128 + cl] + bo;
                    out[(size_t)gr * 128 + cl] = v;
                    t1b[(size_t)slab * ND128 +
                        (size_t)(((w * 8 + m) * 64 + quad * 4 + r + 16 * quad2) * 8 + j)] =
                        (short)f2bf(v);
                    pcs[nt] += v; pcq[nt] += v * v;
                }
            }
        }
#pragma unroll
    for (int nt = 0; nt < 2; ++nt) {
        atomicAdd(&csum[w * 32 + nt * 16 + c], pcs[nt]);
        atomicAdd(&csq[w * 32 + nt * 16 + c], pcq[nt]);
    }
    __syncthreads();
    if (tid < 128) {
        atomicAdd(bn + tid, csum[tid]);
        atomicAdd(bn + 128 + tid, csq[tid]);
    }
}

// --- fold BN1 into W1/bias -------------------------------------------------
__global__ __launch_bounds__(256) void k_fold1(
    const float* __restrict__ bn, const float* __restrict__ g1,
    const float* __restrict__ bb1, const float* __restrict__ W1,
    const float* __restrict__ b1, short* __restrict__ W1b,
    float* __restrict__ badj, float* __restrict__ sfold,
    float* __restrict__ bfold, int N)
{
    __shared__ float s1s[128], b1s[128];
    const int tid = threadIdx.x;
    if (tid < 128) {
        float invN = 1.f / (float)N;
        float mu = bn[tid] * invN;
        float var = bn[128 + tid] * invN - mu * mu;
        float s = g1[tid] * rsqrtf(var + 1e-5f);
        s1s[tid] = s; b1s[tid] = bb1[tid] - mu * s;
        sfold[tid] = s; bfold[tid] = b1s[tid];
    }
    __syncthreads();
    const int o = tid;
    float bsum = b1[o];
    const int nt = o >> 4, lanelow = o & 15;
    for (int i2 = 0; i2 < 128; ++i2) {
        float wv = W1[(size_t)o * 128 + i2];
        bsum = fmaf(wv, b1s[i2], bsum);
        int kb = i2 >> 5, quad = (i2 >> 3) & 3, j = i2 & 7;
        W1b[(size_t)(((nt * 4 + kb) * 64 + lanelow + 16 * quad) * 8 + j)] =
            (short)f2bf(wv * s1s[i2]);
    }
    badj[o] = bsum;
}

// --- FFN1: u = relu(t1b @ W1s^T + badj), bf16 frag order (K=256 layout). ---
__global__ __launch_bounds__(256) void k_ffn1(
    const short* __restrict__ t1b, const short* __restrict__ W1b,
    const float* __restrict__ badj, short* __restrict__ ub, int N)
{
    const int slab = blockIdx.x, ch = blockIdx.y;
    const int w = threadIdx.x >> 6, lane = threadIdx.x & 63;
    const short* A = t1b + (size_t)slab * ND128;

    bf8 bfr[2][4];
#pragma unroll
    for (int nt = 0; nt < 2; ++nt)
#pragma unroll
        for (int kb = 0; kb < 4; ++kb) {
            int ntg = ch * 8 + 2 * w + nt;
            bfr[nt][kb] = *(const bf8*)(W1b + (size_t)((ntg * 4 + kb) * 64 + lane) * 8);
        }

    f4 acc[8][2];
    f4 zero = {0.f, 0.f, 0.f, 0.f};
#pragma unroll
    for (int m = 0; m < 8; ++m) { acc[m][0] = zero; acc[m][1] = zero; }
#pragma unroll
    for (int m = 0; m < 8; ++m) {
#pragma unroll
        for (int kb = 0; kb < 4; ++kb) {
            bf8 a = *(const bf8*)(A + (size_t)((kb * 8 + m) * 64 + lane) * 8);
            acc[m][0] = __builtin_amdgcn_mfma_f32_16x16x32_bf16(a, bfr[0][kb], acc[m][0], 0, 0, 0);
            acc[m][1] = __builtin_amdgcn_mfma_f32_16x16x32_bf16(a, bfr[1][kb], acc[m][1], 0, 0, 0);
        }
    }

    const int c = lane & 15, quad = lane >> 4;
    const int kbu = ch * 4 + w;
#pragma unroll
    for (int m = 0; m < 8; ++m)
#pragma unroll
        for (int nt = 0; nt < 2; ++nt) {
            int colg = ch * 128 + w * 32 + nt * 16 + c;
            float ba = badj[colg];
            int quad2 = nt * 2 + (c >> 3), j = c & 7;
#pragma unroll
            for (int r = 0; r < 4; ++r) {
                int gr = slab * 128 + m * 16 + quad * 4 + r;
                if (gr < N) {
                    float v = fmaxf(acc[m][nt][r] + ba, 0.f);
                    ub[(size_t)slab * 32768 +
                       (size_t)(((kbu * 8 + m) * 64 + quad * 4 + r + 16 * quad2) * 8 + j)] =
                        (short)f2bf(v);
                }
            }
        }
}

// --- FFN2: t2 = (s1*t1 + b1v) + u @ W2^T + b2, in place; BN2 sums. ---------
__global__ __launch_bounds__(256) void k_ffn2(
    const short* __restrict__ ub, const short* __restrict__ W2b,
    const float* __restrict__ sfold, const float* __restrict__ bfold,
    const float* __restrict__ b2, float* __restrict__ out,
    float* __restrict__ bn, int N)
{
    __shared__ float csum[128], csq[128], sS[128], sB[128];
    const int tid = threadIdx.x, slab = blockIdx.x;
    const int w = tid >> 6, lane = tid & 63;
    if (tid < 128) {
        csum[tid] = 0.f; csq[tid] = 0.f;
        sS[tid] = sfold[tid]; sB[tid] = bfold[tid] + b2[tid];
    }
    __syncthreads();
    const short* A = ub + (size_t)slab * 32768;

    bf8 bfr[2][8];
#pragma unroll
    for (int nt = 0; nt < 2; ++nt)
#pragma unroll
        for (int kb = 0; kb < 8; ++kb)
            bfr[nt][kb] = *(const bf8*)(W2b + (size_t)(((2 * w + nt) * 8 + kb) * 64 + lane) * 8);

    f4 acc[8][2];
    f4 zero = {0.f, 0.f, 0.f, 0.f};
#pragma unroll
    for (int m = 0; m < 8; ++m) { acc[m][0] = zero; acc[m][1] = zero; }
#pragma unroll
    for (int m = 0; m < 8; ++m) {
#pragma unroll
        for (int kb = 0; kb < 8; ++kb) {
            bf8 a = *(const bf8*)(A + (size_t)((kb * 8 + m) * 64 + lane) * 8);
            acc[m][0] = __builtin_amdgcn_mfma_f32_16x16x32_bf16(a, bfr[0][kb], acc[m][0], 0, 0, 0);
            acc[m][1] = __builtin_amdgcn_mfma_f32_16x16x32_bf16(a, bfr[1][kb], acc[m][1], 0, 0, 0);
        }
    }

    const int c = lane & 15, quad = lane >> 4;
    float pcs[2] = {0.f, 0.f}, pcq[2] = {0.f, 0.f};
#pragma unroll
    for (int m = 0; m < 8; ++m)
#pragma unroll
        for (int nt = 0; nt < 2; ++nt) {
            int cl = w * 32 + nt * 16 + c;
            float ss = sS[cl], sb = sB[cl];
#pragma unroll
            for (int r = 0; r < 4; ++r) {
                int gr = slab * 128 + m * 16 + quad * 4 + r;
                if (gr < N) {
                    size_t gi = (size_t)gr * 128 + cl;
                    float v = acc[m][nt][r] + fmaf(ss, out[gi], sb);
                    out[gi] = v;
                    pcs[nt] += v; pcq[nt] += v * v;
                }
            }
        }
#pragma unroll
    for (int nt = 0; nt < 2; ++nt) {
        atomicAdd(&csum[w * 32 + nt * 16 + c], pcs[nt]);
        atomicAdd(&csq[w * 32 + nt * 16 + c], pcq[nt]);
    }
    __syncthreads();
    if (tid < 128) {
        atomicAdd(bn + 256 + tid, csum[tid]);
        atomicAdd(bn + 384 + tid, csq[tid]);
    }
}

// --- BN2 normalize in place ------------------------------------------------
__global__ __launch_bounds__(256) void k_bn2(
    float* __restrict__ out, const float* __restrict__ bn,
    const float* __restrict__ g2, const float* __restrict__ bb2, int N)
{
    __shared__ float sS[128], sB[128];
    const int tid = threadIdx.x;
    if (tid < 128) {
        float invN = 1.f / (float)N;
        float mu = bn[256 + tid] * invN;
        float var = bn[384 + tid] * invN - mu * mu;
        float scl = g2[tid] * rsqrtf(var + 1e-5f);
        sS[tid] = scl;
        sB[tid] = bb2[tid] - mu * scl;
    }
    __syncthreads();
    size_t idx = (size_t)blockIdx.x * 256 + tid;
    size_t total = (size_t)N * 32;
    if (idx < total) {
        int c0 = (int)((idx * 4) & 127);
        float4 v = *(const float4*)(out + idx * 4);
        v.x = fmaf(v.x, sS[c0 + 0], sB[c0 + 0]);
        v.y = fmaf(v.y, sS[c0 + 1], sB[c0 + 1]);
        v.z = fmaf(v.z, sS[c0 + 2], sB[c0 + 2]);
        v.w = fmaf(v.w, sS[c0 + 3], sB[c0 + 3]);
        *(float4*)(out + idx * 4) = v;
    }
}

extern "C" void kernel_launch(void* const* d_in, const int* in_sizes, int n_in,
                              void* d_out, int out_size, void* d_ws, size_t ws_size,
                              hipStream_t stream)
{
    const float* h   = (const float*)d_in[0];
    const int*   src = (const int*)d_in[1];
    const int*   dst = (const int*)d_in[2];
    const float* WQ  = (const float*)d_in[3];
    const float* WK  = (const float*)d_in[4];
    const float* WV  = (const float*)d_in[5];
    const float* WO  = (const float*)d_in[6];
    const float* bO  = (const float*)d_in[7];
    const float* W1  = (const float*)d_in[8];
    const float* b1  = (const float*)d_in[9];
    const float* W2  = (const float*)d_in[10];
    const float* b2  = (const float*)d_in[11];
    const float* g1  = (const float*)d_in[12];
    const float* bb1 = (const float*)d_in[13];
    const float* g2  = (const float*)d_in[14];
    const float* bb2 = (const float*)d_in[15];
    float* out = (float*)d_out;

    const int N = in_sizes[0] / 128;
    const int E = in_sizes[1];
    const int slabs = (N + 127) / 128;
    const int nsb = (N + 2047) / 2048;         // scan blocks
    const size_t B1 = (size_t)slabs * 32768;   // bytes of one bf16 N_pad x 128 buffer

    char* Wp = (char*)d_ws;
    short* hb  = (short*)Wp;                         // -> attnf after qkv
    unsigned short* Qb = (unsigned short*)(Wp + B1);
    unsigned short* Kb = (unsigned short*)(Wp + 2 * B1);
    unsigned short* Vb = (unsigned short*)(Wp + 3 * B1);
    short* t1b = (short*)(Wp + 3 * B1);              // overlays Vb (dead after attn)
    short* ub  = (short*)(Wp + B1);                  // overlays Qb+Kb (dead after attn)
    const size_t base = 4 * B1;
    short* Wqb = (short*)(Wp + base);
    short* Wkb = (short*)(Wp + base + 32768);
    short* Wvb = (short*)(Wp + base + 65536);
    short* Wob = (short*)(Wp + base + 98304);
    short* W1b = (short*)(Wp + base + 131072);
    short* W2b = (short*)(Wp + base + 196608);
    float* badj  = (float*)(Wp + base + 262144);
    float* sfold = (float*)(Wp + base + 263168);
    float* bfold = (float*)(Wp + base + 263680);
    float* bn    = (float*)(Wp + base + 264192);     // 512 floats, zeroed
    int* cursor  = (int*)(Wp + base + 266240);       // N ints, zeroed (contig w/ bn)
    int* rowptr  = (int*)(Wp + base + 266240 + (size_t)N * 4);
    int* csr     = (int*)(Wp + base + 266240 + (size_t)N * 8 + 8);
    int* bsum    = (int*)((char*)csr + (size_t)E * 4);
    int* boff    = bsum + 64;

    hipMemsetAsync(bn, 0, 2048 + (size_t)N * 4, stream);

    k_cast_h<<<slabs, 256, 0, stream>>>(h, hb, N);
    k_cast_w<<<6, 256, 0, stream>>>(WQ, WK, WV, WO, W2, Wqb, Wkb, Wvb, Wob, W2b);
    k_qkv<<<dim3(slabs, 3), 256, 0, stream>>>(hb, Wqb, Wkb, Wvb, Qb, Kb, Vb, N);
    k_hist<<<(E + 255) / 256, 256, 0, stream>>>(dst, cursor, E);
    k_scanA<<<nsb, 256, 0, stream>>>(cursor, bsum, N);
    k_scanB<<<1, 64, 0, stream>>>(bsum, boff, rowptr + N, nsb);
    k_scanC<<<nsb, 256, 0, stream>>>(cursor, boff, rowptr, cursor, N);
    k_scatter<<<(E + 255) / 256, 256, 0, stream>>>(src, dst, cursor, csr, E);
    k_attn<<<(N + 3) / 4, 256, 0, stream>>>(Qb, Kb, Vb, rowptr, csr,
                                            (unsigned short*)hb, N);
    k_oproj<<<slabs, 256, 0, stream>>>((const short*)hb, Wob, h, bO, out, t1b, bn, N);
    k_fold1<<<1, 256, 0, stream>>>(bn, g1, bb1, W1, b1, W1b, badj, sfold, bfold, N);
    k_ffn1<<<dim3(slabs, 2), 256, 0, stream>>>(t1b, W1b, badj, ub, N);
    k_ffn2<<<slabs, 256, 0, stream>>>(ub, W2b, sfold, bfold, b2, out, bn, N);
    k_bn2<<<(int)(((size_t)N * 32 + 255) / 256), 256, 0, stream>>>(out, bn, g2, bb2, N);
}